// Round 11
// baseline (1296.428 us; speedup 1.0000x reference)
//
#include <hip/hip_runtime.h>
#include <hip/hip_bf16.h>
#include <cstddef>

// ---- problem dims ----
#define Bq    16
#define Lq    512
#define Mq    32
#define PREDq 96
#define Pq    16
#define Sq    8
#define Dq    128
#define NSTq  16
#define DCq   4
#define NLq   4
#define Nq    63
#define DIq   256
#define DTRq  8
#define TOKq  32256   // 512*63 == 1008*32
#define BMq   512
#define BNq   1008

typedef __attribute__((ext_vector_type(8))) short short8;
typedef __attribute__((ext_vector_type(4))) float f32x4;
typedef __attribute__((ext_vector_type(2))) float f32x2;
typedef __hip_bfloat16 bf16;

// ---- workspace layout (float offsets) ----
constexpr size_t HSZB      = (size_t)TOKq * Dq;              // bf16 elements per hist buf
constexpr size_t OFF_MEANS = 0;
constexpr size_t OFF_STDS  = 512;
constexpr size_t OFF_PART  = 50176;                          // 12*49152 fp32
constexpr size_t OFF_HISTB = 640000;                         // 9 hist bufs, bf16
constexpr size_t OFF_MIX   = OFF_HISTB + 9 * (HSZB / 2);     // fp32 TOK*128
constexpr size_t OFF_XD    = OFF_MIX + (size_t)TOKq * 128;   // fp32 TOK*80 (unused)
constexpr size_t OFF_XZ2   = OFF_XD + (size_t)TOKq * 80;     // bf16 TOK*1024
constexpr size_t OFF_UC    = OFF_XZ2 + (size_t)TOKq * 512;   // bf16 TOK*512 (unused)
constexpr size_t OFF_LNB   = OFF_UC + (size_t)TOKq * 256;    // bf16 TOK*128
constexpr size_t OFF_WB    = OFF_LNB + (size_t)TOKq * 64;    // bf16 weights
constexpr size_t WS_FLOATS = OFF_WB + 1038336;
// bf16-element offsets inside WB region (contiguous):
constexpr size_t WBE_IN   = 0;           // 12*512*128 = 786432
constexpr size_t WBE_X    = 786432;      // 12*40*256  = 122880
constexpr size_t WBE_OUT  = 909312;      // 12*128*256 = 393216
constexpr size_t WBE_HEAD = 1302528;     // 96*8064    = 774144
constexpr int    WB_TOTAL = 2076672;

__device__ __forceinline__ float silu_f(float v) { return v / (1.f + __expf(-v)); }

// unpack 2 contiguous bf16 (4B) -> 2 floats
__device__ __forceinline__ f32x2 bfup2(const bf16* p) {
    unsigned int v = *(const unsigned int*)p;
    f32x2 r;
    r.x = __uint_as_float(v << 16);
    r.y = __uint_as_float(v & 0xffff0000u);
    return r;
}
__device__ __forceinline__ void bfpack2(float f0, float f1, bf16* dst) {
    bf16 b0 = __float2bfloat16(f0), b1 = __float2bfloat16(f1);
    unsigned int u = (unsigned int)*(unsigned short*)&b0 |
                     ((unsigned int)*(unsigned short*)&b1 << 16);
    *(unsigned int*)dst = u;
}

// ============ fused fp32 -> bf16 weight conversion ============
__global__ __launch_bounds__(256) void f2b_all(const float* __restrict__ w_in,
                                               const float* __restrict__ w_x,
                                               const float* __restrict__ w_out,
                                               const float* __restrict__ w_head,
                                               bf16* __restrict__ d) {
    int i = blockIdx.x * 256 + threadIdx.x;
    if (i >= WB_TOTAL) return;
    float v;
    if (i < 786432)        v = w_in[i];
    else if (i < 909312)   v = w_x[i - 786432];
    else if (i < 1302528)  v = w_out[i - 909312];
    else                   v = w_head[i - 1302528];
    d[i] = __float2bfloat16(v);
}

// ============ stats ============
__global__ __launch_bounds__(256) void stats_kernel(const float* __restrict__ x,
                                                    float* __restrict__ means,
                                                    float* __restrict__ stds) {
    int bm = blockIdx.x; int b = bm >> 5, m = bm & 31;
    int tid = threadIdx.x;
    float s = 0.f, ss = 0.f;
    for (int l = tid; l < Lq; l += 256) {
        float v = x[((size_t)b * Lq + l) * Mq + m];
        s += v; ss += v * v;
    }
#pragma unroll
    for (int o = 32; o >= 1; o >>= 1) { s += __shfl_xor(s, o); ss += __shfl_xor(ss, o); }
    __shared__ float sh0[4], sh1[4];
    if ((tid & 63) == 0) { sh0[tid >> 6] = s; sh1[tid >> 6] = ss; }
    __syncthreads();
    if (tid == 0) {
        float S  = sh0[0] + sh0[1] + sh0[2] + sh0[3];
        float SS = sh1[0] + sh1[1] + sh1[2] + sh1[3];
        float mean = S * (1.f / (float)Lq);
        float var  = (SS - (float)Lq * mean * mean) * (1.f / (float)(Lq - 1));
        means[bm] = mean;
        stds[bm]  = sqrtf(fmaxf(var, 0.f)) + 1e-5f;
    }
}

// ============ patch embed -> hist[0] (bf16) ============
__global__ __launch_bounds__(128) void patch_embed(const float* __restrict__ x,
                                                   const float* __restrict__ means,
                                                   const float* __restrict__ stds,
                                                   const float* __restrict__ pw,
                                                   const float* __restrict__ pb,
                                                   const float* __restrict__ pos,
                                                   bf16* __restrict__ h) {
    int blk = blockIdx.x;
    int bm = blk / Nq, n = blk - bm * Nq;
    int b = bm >> 5, m = bm & 31;
    int d = threadIdx.x;
    __shared__ float sx[Pq];
    if (d < Pq) {
        int l = n * Sq + d;
        sx[d] = (x[((size_t)b * Lq + l) * Mq + m] - means[bm]) / stds[bm];
    }
    __syncthreads();
    float acc = pb[d];
#pragma unroll
    for (int p = 0; p < Pq; p++) acc += sx[p] * pw[d * Pq + p];
    h[(size_t)blk * Dq + d] = __float2bfloat16(acc + pos[n * Dq + d]);
}

// ============ bf16 MFMA GEMM, templated (in_proj l0 + head) ============
template<int CONVM, int KSKIP, int NT, int MR = 128>
__global__ __launch_bounds__(256) void gemm_k(
        const bf16* __restrict__ A, int lda,
        const bf16* __restrict__ Bw, const bf16* __restrict__ Bw2, int ldb,
        const float* __restrict__ resid, int ldr,
        float* __restrict__ C, bf16* __restrict__ Cb, int ldc,
        int M, int N, int Klen, int kstride, size_t csplit,
        int accum, int rowmap,
        int slen, const float* __restrict__ cw, const float* __restrict__ cb,
        int Mhalf, int ahalfcol, int choff, int gsilu,
        bf16* __restrict__ ucout) {
    constexpr int WR = MR / 4;     // rows per wave
    constexpr int MS = WR / 16;    // 16-row MFMA tiles per wave
    __shared__ __align__(16) short Al[MR * 40];
    __shared__ __align__(16) short Bl[NT * 40];
    int tid = threadIdx.x;
    int wave = tid >> 6, lane = tid & 63;
    int m0 = blockIdx.y * MR, n0 = blockIdx.x * NT;
    int kbase = blockIdx.z * kstride;
    constexpr int NS = NT / 16;
    f32x4 acc[MS][NS];
#pragma unroll
    for (int i = 0; i < MS; i++)
#pragma unroll
        for (int j = 0; j < NS; j++) acc[i][j] = (f32x4){0.f, 0.f, 0.f, 0.f};

    int mlane = lane & 15, koff = (lane >> 4) * 8;
    const uint4 Z4 = {0u, 0u, 0u, 0u};

    {
        int ar = tid >> 1, ah = tid & 1;
        int brr = (NT == 128) ? (tid >> 1) : (tid >> 2);
        int bqh = (NT == 128) ? (tid & 1) : (tid & 3);
        uint4 av0, av1, bv0, bv1;
        av0 = av1 = bv0 = bv1 = Z4;
        auto loadAB = [&](int kk0) {
            int gcol = kk0 + ah * 16;
            if (KSKIP && kk0 >= 256) gcol += 256;
            const bf16* asrc = A + (size_t)(m0 + ar) * lda + gcol;
            av0 = *(const uint4*)asrc;
            av1 = *(const uint4*)(asrc + 8);
            const bf16* bb = Bw;
            if (NT == 128) {
                int bc = kk0 + bqh * 16;
                if (KSKIP && kk0 >= 256) { bb = Bw2; bc -= 256; }
                int gn = n0 + brr;
                if (gn < N) {
                    const bf16* bsrc = bb + (size_t)gn * ldb + bc;
                    bv0 = *(const uint4*)bsrc;
                    bv1 = *(const uint4*)(bsrc + 8);
                } else { bv0 = Z4; bv1 = Z4; }
            } else {
                int bc = kk0 + bqh * 8;
                if (KSKIP && kk0 >= 256) { bb = Bw2; bc -= 256; }
                int gn = n0 + brr;
                bv0 = (gn < N) ? *(const uint4*)(bb + (size_t)gn * ldb + bc) : Z4;
            }
        };
        loadAB(kbase);
        for (int k0 = 0; k0 < Klen; k0 += 32) {
            *(uint4*)&Al[ar * 40 + ah * 16]     = av0;
            *(uint4*)&Al[ar * 40 + ah * 16 + 8] = av1;
            if (NT == 128) {
                *(uint4*)&Bl[brr * 40 + bqh * 16]     = bv0;
                *(uint4*)&Bl[brr * 40 + bqh * 16 + 8] = bv1;
            } else {
                *(uint4*)&Bl[brr * 40 + bqh * 8] = bv0;
            }
            __syncthreads();
            if (k0 + 32 < Klen) loadAB(kbase + k0 + 32);
            short8 afr[MS];
#pragma unroll
            for (int ms = 0; ms < MS; ms++)
                afr[ms] = *(const short8*)&Al[(wave * WR + ms * 16 + mlane) * 40 + koff];
#pragma unroll
            for (int ns = 0; ns < NS; ns++) {
                short8 bfr = *(const short8*)&Bl[(ns * 16 + mlane) * 40 + koff];
#pragma unroll
                for (int ms = 0; ms < MS; ms++)
                    acc[ms][ns] = __builtin_amdgcn_mfma_f32_16x16x32_bf16(afr[ms], bfr, acc[ms][ns], 0, 0, 0);
            }
            __syncthreads();
        }
    }

    float* Cz = C + (size_t)blockIdx.z * csplit;
#pragma unroll
    for (int ms = 0; ms < MS; ms++) {
#pragma unroll
        for (int ns = 0; ns < NS; ns++) {
            int n = n0 + ns * 16 + mlane;
            if (n >= N) continue;
#pragma unroll
            for (int r = 0; r < 4; r++) {
                int m = m0 + wave * WR + ms * 16 + (lane >> 4) * 4 + r;
                int orow = m, ocol = n;
                if (rowmap) {                 // (b*63+nn)*32+mm -> (b*32+mm)*63+nn
                    int bn = m >> 5, mm = m & 31;
                    int b = bn / Nq, nn = bn - b * Nq;
                    orow = (b * Mq + mm) * Nq + nn;
                }
                float v = acc[ms][ns][r];
                if (resid) v += resid[(size_t)orow * ldr + ocol];
                if (Cb) {
                    if (gsilu && ((ocol >> 8) & 1)) v = silu_f(v);   // pre-gate z cols
                    Cb[(size_t)orow * ldc + ocol] = __float2bfloat16(v);
                } else {
                    size_t o = (size_t)orow * ldc + ocol;
                    if (accum) Cz[o] += v; else Cz[o] = v;
                }
            }
        }
    }
}

// ============ out_proj GEMM + fused hist-write + next-mix + LN + next in_proj ==
// MR=64, NT=128 (full 128-col rows per block).
// MIXMODE 0: mix_ch(l) -> fused ch in_proj (INPROJ=8 chunks, W rows o1|o2 contiguous).
// MIXMODE 1: mix_tok(l+1) -> fused tok in_proj l+1 (INPROJ=4 chunks).
// MIXMODE 2: ln128 (Norm2D pt1): LN(hist) -> mixout fp32 only (INPROJ=0).
// Second stage: A = LN rows from LDS (same bf16 values), K=128 ascending (same
// MFMA accumulation order as old in_proj gemm_k), z-silu on (col>>8)&1, write XZ2.
template<int KSKIP, int ROWMAP, int MIXMODE, int INPROJ>
__global__ __launch_bounds__(256) void gemm_mix(
        const bf16* __restrict__ A,                 // XZ2, lda=1024
        const bf16* __restrict__ Bw, const bf16* __restrict__ Bw2,  // ldb=256
        const float* __restrict__ resid,            // MIX (pre-LN mamba input)
        bf16* __restrict__ hb, int hwrite, int l,
        const float* __restrict__ mw0, const float* __restrict__ mw1,
        const float* __restrict__ lnw, const float* __restrict__ lnb,
        float* __restrict__ mixout, bf16* __restrict__ lnbout,
        const bf16* __restrict__ Wi, bf16* __restrict__ xzout) {
    constexpr int KLEN = KSKIP ? 512 : 256;
    __shared__ __align__(16) short Al[64 * 40];
    __shared__ __align__(16) short Bl[128 * 40];
    __shared__ __align__(16) bf16 Aln[INPROJ ? 64 * 132 : 1];
    int tid = threadIdx.x;
    int wave = tid >> 6, lane = tid & 63;
    int mlane = lane & 15, koff = (lane >> 4) * 8;
    int m0 = blockIdx.x * 64;

    f32x4 acc[8];
#pragma unroll
    for (int j = 0; j < 8; j++) acc[j] = (f32x4){0.f, 0.f, 0.f, 0.f};

    int ar = tid >> 2, ah = tid & 3;        // A: 64 rows, 4 thr/row, 8 cols each
    int br = tid >> 1, bq = tid & 1;        // B: 128 rows, 2 thr/row, 16 cols each
    uint4 av, bv0, bv1;
    auto loadAB = [&](int kk0) {
        int gcol = kk0 + ah * 8;
        if (KSKIP && kk0 >= 256) gcol += 256;
        av = *(const uint4*)(A + (size_t)(m0 + ar) * 1024 + gcol);
        const bf16* bb = Bw;
        int bc = kk0 + bq * 16;
        if (KSKIP && kk0 >= 256) { bb = Bw2; bc -= 256; }
        const bf16* bsrc = bb + (size_t)br * 256 + bc;
        bv0 = *(const uint4*)bsrc;
        bv1 = *(const uint4*)(bsrc + 8);
    };
    loadAB(0);
    for (int k0 = 0; k0 < KLEN; k0 += 32) {
        *(uint4*)&Al[ar * 40 + ah * 8]      = av;
        *(uint4*)&Bl[br * 40 + bq * 16]     = bv0;
        *(uint4*)&Bl[br * 40 + bq * 16 + 8] = bv1;
        __syncthreads();
        if (k0 + 32 < KLEN) loadAB(k0 + 32);
        short8 a = *(const short8*)&Al[(wave * 16 + mlane) * 40 + koff];
#pragma unroll
        for (int ns = 0; ns < 8; ns++) {
            short8 b = *(const short8*)&Bl[(ns * 16 + mlane) * 40 + koff];
            acc[ns] = __builtin_amdgcn_mfma_f32_16x16x32_bf16(a, b, acc[ns], 0, 0, 0);
        }
        __syncthreads();
    }

    // ---- mix softmax weights (uniform across threads) ----
    float w0[5], w1[4];
    int ct = 0, cg = 0;
    if (MIXMODE == 0) {
        ct = l + 2; cg = l + 1;
        float m0v = -1e30f, m1v = -1e30f;
        for (int i = 0; i < ct; i++) { w0[i] = mw0[l * 5 + i]; m0v = fmaxf(m0v, w0[i]); }
        for (int i = 0; i < cg; i++) { w1[i] = mw1[l * 4 + i]; m1v = fmaxf(m1v, w1[i]); }
        float s0 = 0.f, s1 = 0.f;
        for (int i = 0; i < ct; i++) { w0[i] = __expf(w0[i] - m0v); s0 += w0[i]; }
        for (int i = 0; i < cg; i++) { w1[i] = __expf(w1[i] - m1v); s1 += w1[i]; }
        float i0 = 1.f / s0, i1 = 1.f / s1;
        for (int i = 0; i < ct; i++) w0[i] *= i0;
        for (int i = 0; i < cg; i++) w1[i] *= i1;
    } else if (MIXMODE == 1) {
        int lt = l + 1;
        ct = lt + 1; cg = lt + 1;
        float m0v = -1e30f, m1v = -1e30f;
        for (int i = 0; i < ct; i++) {
            w0[i] = mw0[lt * 4 + i]; w1[i] = mw1[lt * 4 + i];
            m0v = fmaxf(m0v, w0[i]); m1v = fmaxf(m1v, w1[i]);
        }
        float s0 = 0.f, s1 = 0.f;
        for (int i = 0; i < ct; i++) {
            w0[i] = __expf(w0[i] - m0v); s0 += w0[i];
            w1[i] = __expf(w1[i] - m1v); s1 += w1[i];
        }
        float i0 = 1.f / s0, i1 = 1.f / s1;
        for (int i = 0; i < ct; i++) { w0[i] *= i0; w1[i] *= i1; }
    }

    // ---- per-row epilogue: hist write + mix + LN (+ park LN rows in LDS) ----
#pragma unroll
    for (int r = 0; r < 4; r++) {
        int m = m0 + wave * 16 + (lane >> 4) * 4 + r;
        int orow = m;
        if (ROWMAP) {
            int bn = m >> 5, mm = m & 31;
            int b = bn / Nq, nn = bn - b * Nq;
            orow = (b * Mq + mm) * Nq + nn;
        }
        size_t t128 = (size_t)orow * 128;
        float hv[8];
#pragma unroll
        for (int ns = 0; ns < 8; ns++) {
            int col = ns * 16 + mlane;
            float v = acc[ns][r] + resid[t128 + col];
            bf16 hvb = __float2bfloat16(v);
            hb[(size_t)hwrite * HSZB + t128 + col] = hvb;
            hv[ns] = __bfloat162float(hvb);
        }
        float mixv[8];
        if (MIXMODE == 2) {
#pragma unroll
            for (int ns = 0; ns < 8; ns++) mixv[ns] = hv[ns];
        } else if (MIXMODE == 0) {
#pragma unroll
            for (int ns = 0; ns < 8; ns++) mixv[ns] = 0.f;
            for (int i = 0; i < ct; i++) {
                int bi = (i == 0) ? 0 : i;
                if (bi == hwrite) {
#pragma unroll
                    for (int ns = 0; ns < 8; ns++) mixv[ns] += w0[i] * hv[ns];
                } else {
                    const bf16* yp = hb + (size_t)bi * HSZB + t128;
#pragma unroll
                    for (int ns = 0; ns < 8; ns++)
                        mixv[ns] += w0[i] * __bfloat162float(yp[ns * 16 + mlane]);
                }
            }
            for (int i = 0; i < cg; i++) {
                int bi = (i == 0) ? 0 : 4 + i;
                const bf16* yp = hb + (size_t)bi * HSZB + t128;
#pragma unroll
                for (int ns = 0; ns < 8; ns++)
                    mixv[ns] += w1[i] * __bfloat162float(yp[ns * 16 + mlane]);
            }
        } else {  // MIXMODE 1
#pragma unroll
            for (int ns = 0; ns < 8; ns++) mixv[ns] = 0.f;
            for (int i = 0; i < ct; i++) {
                int bt = (i == 0) ? 0 : i;
                int bc = (i == 0) ? 0 : 4 + i;
                const bf16* ytp = hb + (size_t)bt * HSZB + t128;
                if (bc == hwrite) {
#pragma unroll
                    for (int ns = 0; ns < 8; ns++)
                        mixv[ns] += w0[i] * __bfloat162float(ytp[ns * 16 + mlane]) + w1[i] * hv[ns];
                } else {
                    const bf16* ycp = hb + (size_t)bc * HSZB + t128;
#pragma unroll
                    for (int ns = 0; ns < 8; ns++)
                        mixv[ns] += w0[i] * __bfloat162float(ytp[ns * 16 + mlane]) +
                                    w1[i] * __bfloat162float(ycp[ns * 16 + mlane]);
                }
            }
        }
        // LN row-reduce across the 16-lane group (xor 1,2,4,8)
        float s = 0.f, ss = 0.f;
#pragma unroll
        for (int ns = 0; ns < 8; ns++) { s += mixv[ns]; ss += mixv[ns] * mixv[ns]; }
#pragma unroll
        for (int o = 8; o >= 1; o >>= 1) { s += __shfl_xor(s, o); ss += __shfl_xor(ss, o); }
        float mean = s * (1.f / 128.f);
        float var  = ss * (1.f / 128.f) - mean * mean;
        float rstd = rsqrtf(var + 1e-5f);
        if (MIXMODE == 2) {
#pragma unroll
            for (int ns = 0; ns < 8; ns++) {
                int col = ns * 16 + mlane;
                mixout[t128 + col] = (mixv[ns] - mean) * rstd * lnw[col] + lnb[col];
            }
        } else {
#pragma unroll
            for (int ns = 0; ns < 8; ns++) mixout[t128 + ns * 16 + mlane] = mixv[ns];
            size_t lbase;
            if (MIXMODE == 0) {
                int bm = orow / Nq, nn = orow - bm * Nq, b = bm >> 5, mq = bm & 31;
                lbase = (size_t)((b * Nq + nn) * Mq + mq) * 128;
            } else {
                lbase = t128;
            }
#pragma unroll
            for (int ns = 0; ns < 8; ns++) {
                int col = ns * 16 + mlane;
                bf16 lv = __float2bfloat16((mixv[ns] - mean) * rstd * lnw[col] + lnb[col]);
                if (INPROJ) Aln[(m - m0) * 132 + col] = lv;
                if (lnbout) lnbout[lbase + col] = lv;
            }
        }
    }

    // ---- second stage: in_proj = Aln @ Wi^T  (M=64, N=INPROJ*128, K=128) ----
    if (INPROJ) {
        int abr = tid >> 1, abq = tid & 1;
        uint4 wv0, wv1;
        auto loadW = [&](int it) {
            int nc = it >> 2, kk = (it & 3) * 32;
            const bf16* src = Wi + (size_t)(nc * 128 + abr) * 128 + kk + abq * 16;
            wv0 = *(const uint4*)src;
            wv1 = *(const uint4*)(src + 8);
        };
        loadW(0);
        f32x4 acc2[8];
        for (int it = 0; it < INPROJ * 4; it++) {
            int nc = it >> 2, kk = (it & 3) * 32;
            if ((it & 3) == 0) {
#pragma unroll
                for (int j = 0; j < 8; j++) acc2[j] = (f32x4){0.f, 0.f, 0.f, 0.f};
            }
            __syncthreads();
            *(uint4*)&Bl[abr * 40 + abq * 16]     = wv0;
            *(uint4*)&Bl[abr * 40 + abq * 16 + 8] = wv1;
            __syncthreads();
            if (it + 1 < INPROJ * 4) loadW(it + 1);
            short8 a = *(const short8*)&Aln[(wave * 16 + mlane) * 132 + kk + koff];
#pragma unroll
            for (int ns = 0; ns < 8; ns++) {
                short8 b = *(const short8*)&Bl[(ns * 16 + mlane) * 40 + koff];
                acc2[ns] = __builtin_amdgcn_mfma_f32_16x16x32_bf16(a, b, acc2[ns], 0, 0, 0);
            }
            if ((it & 3) == 3) {
#pragma unroll
                for (int r = 0; r < 4; r++) {
                    int m = m0 + wave * 16 + (lane >> 4) * 4 + r;
                    int xrow;
                    if (MIXMODE == 0) {
                        int bm = m / Nq, nn = m - bm * Nq;
                        xrow = ((bm >> 5) * Nq + nn) * Mq + (bm & 31);
                    } else {
                        int bn = m >> 5, mm = m & 31;
                        int b = bn / Nq, nn = bn - b * Nq;
                        xrow = (b * Mq + mm) * Nq + nn;
                    }
#pragma unroll
                    for (int ns = 0; ns < 8; ns++) {
                        int col = nc * 128 + ns * 16 + mlane;
                        float v = acc2[ns][r];
                        if ((col >> 8) & 1) v = silu_f(v);   // z columns
                        xzout[(size_t)xrow * 1024 + col] = __float2bfloat16(v);
                    }
                }
            }
        }
    }
}

// ============ FULLY FUSED mamba core (R7-proven version) ============
template<int SLEN, int ROWS>
__global__ __launch_bounds__(256) void scan_f(bf16* __restrict__ xz2,
                                              const float* __restrict__ dtw,
                                              const float* __restrict__ dtb,
                                              const float* __restrict__ alog,
                                              const float* __restrict__ Dp,
                                              const float* __restrict__ cw,
                                              const float* __restrict__ cb,
                                              const bf16* __restrict__ xw,
                                              const bf16* __restrict__ xw2,
                                              int nb, int dual) {
    constexpr int UST = 264;                      // u row stride in bf16 (528B)
    __shared__ __align__(16) bf16 u_l[ROWS * UST];
    __shared__ __align__(16) float qlds[SLEN * 40];
    int bid = blockIdx.x;
    int half = (dual && bid >= nb) ? 1 : 0;
    int row = bid - half * nb;
    int rev = half;
    int tid = threadIdx.x;
    int d = tid;
    int wave = tid >> 6, lane = tid & 63;
    int mlane = lane & 15, koff = (lane >> 4) * 8;

    size_t xbase = (size_t)row * SLEN * 1024 + (size_t)half * 512 + d;
    size_t base  = xbase;

    float ucur[8], zcur[8];
#pragma unroll
    for (int i = 0; i < 8; i++) {
        int s = rev ? (SLEN - 1 - i) : i;
        zcur[i] = __bfloat162float(xz2[base + (size_t)s * 1024 + 256]);
    }
    const float* al = alog + half * 4096 + d * 16;
    float a0 = -__expf(al[0]);
    bool fast = true;
#pragma unroll
    for (int j = 1; j < 16; j++) {
        float aj = -__expf(al[j]);
        fast = fast && (fabsf(aj - a0 * (float)(j + 1)) < 1e-5f * (float)(j + 1));
    }
    f32x2 dw2[4];
#pragma unroll
    for (int r = 0; r < 4; r++)
        dw2[r] = (f32x2){dtw[half * 2048 + d * 8 + 2 * r], dtw[half * 2048 + d * 8 + 2 * r + 1]};
    float dbv = dtb[half * 256 + d], Dv = Dp[half * 256 + d];

    {
        float c0 = cw[half * 1024 + d * 4 + 0];
        float c1 = cw[half * 1024 + d * 4 + 1];
        float c2 = cw[half * 1024 + d * 4 + 2];
        float c3 = cw[half * 1024 + d * 4 + 3];
        float cbv = cb[half * 256 + d];
        constexpr int NCC = (SLEN + 7) / 8;
        float xc[8], xn[8];
#pragma unroll
        for (int i = 0; i < 8; i++) {
            int st = i < SLEN ? i : SLEN - 1;
            int s = rev ? (SLEN - 1 - st) : st;
            xc[i] = __bfloat162float(xz2[xbase + (size_t)s * 1024]);
        }
        float g1 = 0.f, g2 = 0.f, g3 = 0.f;
        for (int c = 0; c < NCC; c++) {
            if (c + 1 < NCC) {
#pragma unroll
                for (int i = 0; i < 8; i++) {
                    int st = (c + 1) * 8 + i; st = st < SLEN ? st : SLEN - 1;
                    int s = rev ? (SLEN - 1 - st) : st;
                    xn[i] = __bfloat162float(xz2[xbase + (size_t)s * 1024]);
                }
            }
#pragma unroll
            for (int i = 0; i < 8; i++) {
                int st = c * 8 + i;
                if (st < SLEN) {
                    int s = rev ? (SLEN - 1 - st) : st;
                    float cur = xc[i];
                    float ac = cbv;
                    if (st >= 3) ac += c0 * g3;
                    if (st >= 2) ac += c1 * g2;
                    if (st >= 1) ac += c2 * g1;
                    ac += c3 * cur;
                    bf16 ub = __float2bfloat16(silu_f(ac));
                    u_l[s * UST + d] = ub;
                    if (c == 0) ucur[i] = __bfloat162float(ub);
                    g3 = g2; g2 = g1; g1 = cur;
                }
            }
#pragma unroll
            for (int i = 0; i < 8; i++) xc[i] = xn[i];
        }
        for (int s = SLEN; s < ROWS; s++) u_l[s * UST + d] = __float2bfloat16(0.f);
    }
    __syncthreads();

    {
        const bf16* xwp = half ? xw2 : xw;
        constexpr int RT = ROWS / 16;
        constexpr int NTILES = RT * 3;
        const short8 bz = {0, 0, 0, 0, 0, 0, 0, 0};
        for (int tI = wave; tI < NTILES; tI += 4) {
            int tr = tI / 3, tc = tI - tr * 3;
            int gn = tc * 16 + mlane;
            bool okn = gn < 40;
            f32x4 acc = (f32x4){0.f, 0.f, 0.f, 0.f};
#pragma unroll
            for (int kk = 0; kk < 256; kk += 32) {
                short8 a = *(const short8*)&u_l[(tr * 16 + mlane) * UST + kk + koff];
                short8 b = okn ? *(const short8*)(xwp + (size_t)gn * 256 + kk + koff) : bz;
                acc = __builtin_amdgcn_mfma_f32_16x16x32_bf16(a, b, acc, 0, 0, 0);
            }
#pragma unroll
            for (int r = 0; r < 4; r++) {
                int s = tr * 16 + (lane >> 4) * 4 + r;
                if (okn && s < SLEN) qlds[s * 40 + gn] = acc[r];
            }
        }
    }

    f32x2 h2[8];
#pragma unroll
    for (int j = 0; j < 8; j++) h2[j] = (f32x2){0.f, 0.f};
    constexpr int NCH = (SLEN + 7) / 8;
    __syncthreads();

    float unxt[8], znxt[8];
    for (int c = 0; c < NCH; c++) {
        if (c + 1 < NCH) {
#pragma unroll
            for (int i = 0; i < 8; i++) {
                int st = (c + 1) * 8 + i; st = st < SLEN ? st : SLEN - 1;
                int s = rev ? (SLEN - 1 - st) : st;
                unxt[i] = __bfloat162float(u_l[s * UST + d]);
                znxt[i] = __bfloat162float(xz2[base + (size_t)s * 1024 + 256]);
            }
        }
#pragma unroll
        for (int i = 0; i < 8; i++) {
            int st = c * 8 + i;
            if (st < SLEN) {
                int s = rev ? (SLEN - 1 - st) : st;
                const float4* qv = (const float4*)&qlds[s * 40];
                float4 qa = qv[0], qb = qv[1];
                float uc_v = ucur[i];
                f32x2 acc2 = dw2[0] * (f32x2){qa.x, qa.y};
                acc2 += dw2[1] * (f32x2){qa.z, qa.w};
                acc2 += dw2[2] * (f32x2){qb.x, qb.y};
                acc2 += dw2[3] * (f32x2){qb.z, qb.w};
                float dtv = dbv + acc2.x + acc2.y;
                dtv = fmaxf(dtv, 0.f) + __logf(1.f + __expf(-fabsf(dtv)));
                float du = dtv * uc_v;
                float y;
                if (fast) {
                    float p1 = __expf(dtv * a0);
                    float p2 = p1 * p1;
                    f32x2 pp = (f32x2){p2, p2};
                    f32x2 e2[8];
                    e2[0] = (f32x2){p1, p2};
#pragma unroll
                    for (int j = 1; j < 8; j++) e2[j] = e2[j - 1] * pp;
                    f32x2 du2 = (f32x2){du, du};
                    f32x2 y2 = (f32x2){0.f, 0.f};
                    float4 B0 = qv[2], B1 = qv[3], B2 = qv[4], B3 = qv[5];
                    float4 C0 = qv[6], C1 = qv[7], C2 = qv[8], C3 = qv[9];
                    f32x2 bb[8] = {{B0.x, B0.y}, {B0.z, B0.w}, {B1.x, B1.y}, {B1.z, B1.w},
                                   {B2.x, B2.y}, {B2.z, B2.w}, {B3.x, B3.y}, {B3.z, B3.w}};
                    f32x2 cc[8] = {{C0.x, C0.y}, {C0.z, C0.w}, {C1.x, C1.y}, {C1.z, C1.w},
                                   {C2.x, C2.y}, {C2.z, C2.w}, {C3.x, C3.y}, {C3.z, C3.w}};
#pragma unroll
                    for (int j = 0; j < 8; j++) {
                        h2[j] = h2[j] * e2[j] + du2 * bb[j];
                        y2 += h2[j] * cc[j];
                    }
                    y = y2.x + y2.y;
                } else {
                    const float* q = &qlds[s * 40];
                    y = 0.f;
#pragma unroll
                    for (int j = 0; j < 16; j++) {
                        float e = __expf(dtv * (-__expf(al[j])));
                        float hh = h2[j >> 1][j & 1];
                        hh = hh * e + du * q[8 + j];
                        h2[j >> 1][j & 1] = hh;
                        y += hh * q[24 + j];
                    }
                }
                xz2[base + (size_t)s * 1024] =
                    __float2bfloat16((y + uc_v * Dv) * zcur[i]);
            }
        }
#pragma unroll
        for (int i = 0; i < 8; i++) { ucur[i] = unxt[i]; zcur[i] = znxt[i]; }
    }
}

// ============ token mix + LN (standalone, used for layer 0 only) ============
__global__ __launch_bounds__(256) void mix_ln_tok(const bf16* __restrict__ hb,
                                                 float* __restrict__ mixb, bf16* __restrict__ lnb_out,
                                                 const float* __restrict__ alpha,
                                                 const float* __restrict__ beta,
                                                 const float* __restrict__ lnw,
                                                 const float* __restrict__ lnb, int l) {
    int t = blockIdx.x * 4 + (threadIdx.x >> 6), d = threadIdx.x & 63;
    int cnt = l + 1;
    float aw[4], bw[4];
    float amax = -1e30f, bmax = -1e30f;
    for (int i = 0; i < cnt; i++) {
        aw[i] = alpha[l * 4 + i]; bw[i] = beta[l * 4 + i];
        amax = fmaxf(amax, aw[i]); bmax = fmaxf(bmax, bw[i]);
    }
    float as = 0.f, bs = 0.f;
    for (int i = 0; i < cnt; i++) {
        aw[i] = __expf(aw[i] - amax); as += aw[i];
        bw[i] = __expf(bw[i] - bmax); bs += bw[i];
    }
    float ai = 1.f / as, bi = 1.f / bs;
    float v0 = 0.f, v1 = 0.f;
    for (int i = 0; i < cnt; i++) {
        const bf16* yt = hb + (size_t)(i == 0 ? 0 : i) * HSZB + (size_t)t * 128 + 2 * d;
        const bf16* yc = hb + (size_t)(i == 0 ? 0 : 4 + i) * HSZB + (size_t)t * 128 + 2 * d;
        f32x2 vt = bfup2(yt), vc = bfup2(yc);
        float wa = aw[i] * ai, wb = bw[i] * bi;
        v0 += wa * vt.x + wb * vc.x;
        v1 += wa * vt.y + wb * vc.y;
    }
    *(f32x2*)&mixb[(size_t)t * 128 + 2 * d] = (f32x2){v0, v1};
    float s = v0 + v1, ss = v0 * v0 + v1 * v1;
#pragma unroll
    for (int o = 32; o >= 1; o >>= 1) { s += __shfl_xor(s, o); ss += __shfl_xor(ss, o); }
    float mean = s * (1.f / 128.f);
    float var  = ss * (1.f / 128.f) - mean * mean;
    float rstd = rsqrtf(var + 1e-5f);
    f32x2 w2 = *(const f32x2*)&lnw[2 * d];
    f32x2 b2 = *(const f32x2*)&lnb[2 * d];
    bfpack2((v0 - mean) * rstd * w2.x + b2.x,
            (v1 - mean) * rstd * w2.y + b2.y,
            lnb_out + (size_t)t * 128 + 2 * d);
}

// ============ LN over N=63, bf16 out ============
__global__ __launch_bounds__(256) void final_ln2(const float* __restrict__ in,
                                                 const float* __restrict__ w2,
                                                 const float* __restrict__ b2,
                                                 bf16* __restrict__ out) {
    int idx = blockIdx.x * 256 + threadIdx.x;
    if (idx >= BMq * Dq) return;
    int bm = idx >> 7, d = idx & 127;
    float s = 0.f, ss = 0.f;
    for (int n = 0; n < Nq; n++) {
        float v = in[((size_t)bm * Nq + n) * 128 + d];
        s += v; ss += v * v;
    }
    float mean = s * (1.f / (float)Nq);
    float var  = ss * (1.f / (float)Nq) - mean * mean;
    float rstd = rsqrtf(var + 1e-5f);
    for (int n = 0; n < Nq; n++) {
        float v = in[((size_t)bm * Nq + n) * 128 + d];
        out[((size_t)bm * Nq + n) * 128 + d] = __float2bfloat16((v - mean) * rstd * w2[n] + b2[n]);
    }
}

// ============ final: split-K reduce + bias + rescale + transpose ============
__global__ __launch_bounds__(256) void finalize_kernel(const float* __restrict__ part,
                                                       const float* __restrict__ bias,
                                                       const float* __restrict__ means,
                                                       const float* __restrict__ stds,
                                                       float* __restrict__ out) {
    int idx = blockIdx.x * 256 + threadIdx.x;
    if (idx >= Bq * PREDq * Mq) return;
    int b = idx / (PREDq * Mq);
    int r = idx - b * PREDq * Mq;
    int pr = r >> 5, m = r & 31;
    int bm = b * Mq + m;
    float s = bias[pr];
#pragma unroll
    for (int z = 0; z < 12; z++) s += part[(size_t)z * BMq * PREDq + (size_t)bm * PREDq + pr];
    out[idx] = s * stds[bm] + means[bm];
}

extern "C" void kernel_launch(void* const* d_in, const int* in_sizes, int n_in,
                              void* d_out, int out_size, void* d_ws, size_t ws_size,
                              hipStream_t stream) {
    if (ws_size < WS_FLOATS * sizeof(float)) return;

    const float* x          = (const float*)d_in[0];
    const float* patch_w    = (const float*)d_in[1];
    const float* patch_b    = (const float*)d_in[2];
    const float* pos_embed  = (const float*)d_in[3];
    const float* alpha      = (const float*)d_in[4];
    const float* beta       = (const float*)d_in[5];
    const float* theta      = (const float*)d_in[6];
    const float* gamma      = (const float*)d_in[7];
    const float* tok_norm_w = (const float*)d_in[8];
    const float* tok_norm_b = (const float*)d_in[9];
    const float* ch_norm_w  = (const float*)d_in[10];
    const float* ch_norm_b  = (const float*)d_in[11];
    const float* in_proj_w  = (const float*)d_in[12];
    const float* conv_w     = (const float*)d_in[13];
    const float* conv_b     = (const float*)d_in[14];
    const float* x_proj_w   = (const float*)d_in[15];
    const float* dt_proj_w  = (const float*)d_in[16];
    const float* dt_proj_b  = (const float*)d_in[17];
    const float* A_log      = (const float*)d_in[18];
    const float* D_ssm      = (const float*)d_in[19];
    const float* out_proj_w = (const float*)d_in[20];
    const float* n2d_w1     = (const float*)d_in[21];
    const float* n2d_b1     = (const float*)d_in[22];
    const float* n2d_w2     = (const float*)d_in[23];
    const float* n2d_b2     = (const float*)d_in[24];
    const float* head_w     = (const float*)d_in[25];
    const float* head_b     = (const float*)d_in[26];

    float* W   = (float*)d_ws;
    float* out = (float*)d_out;
    bf16* WB   = (bf16*)(W + OFF_WB);
    bf16* HB   = (bf16*)(W + OFF_HISTB);
    bf16* LNB  = (bf16*)(W + OFF_LNB);
    bf16* XZ2  = (bf16*)(W + OFF_XZ2);
    float* MIX = W + OFF_MIX;

    f2b_all<<<(WB_TOTAL + 255) / 256, 256, 0, stream>>>(
        in_proj_w, x_proj_w, out_proj_w, head_w, WB);

    stats_kernel<<<BMq, 256, 0, stream>>>(x, W + OFF_MEANS, W + OFF_STDS);
    patch_embed<<<TOKq, 128, 0, stream>>>(x, W + OFF_MEANS, W + OFF_STDS,
                                          patch_w, patch_b, pos_embed, HB);

    // layer-0 token mix (producer is patch_embed) + standalone in_proj tok l0
    mix_ln_tok<<<TOKq / 4, 256, 0, stream>>>(HB, MIX, LNB, alpha, beta,
                                             tok_norm_w, tok_norm_b, 0);
    gemm_k<0, 0, 128><<<dim3(4, 252, 1), 256, 0, stream>>>(
        LNB, 128, WB + WBE_IN, nullptr, 128, nullptr, 0,
        nullptr, XZ2, 1024, TOKq, 512, 128, 0, 0, 0, 0,
        0, nullptr, nullptr, 0, 0, 0, 1, nullptr);

    for (int l = 0; l < NLq; l++) {
        size_t o0 = (size_t)(l * 3 + 0), o1 = (size_t)(l * 3 + 1), o2 = (size_t)(l * 3 + 2);

        // ================= token mamba =================
        scan_f<Nq, 64><<<BMq, 256, 0, stream>>>(
            XZ2, dt_proj_w + o0 * 2048, dt_proj_b + o0 * 256,
            A_log + o0 * 4096, D_ssm + o0 * 256,
            conv_w + o0 * 1024, conv_b + o0 * 256,
            WB + WBE_X + o0 * 10240, nullptr, BMq, 0);
        // out_proj tok + fused mix_ch(l) + LN + fused ch in_proj (o1|o2 contiguous)
        gemm_mix<0, 0, 0, 8><<<504, 256, 0, stream>>>(
            XZ2, WB + WBE_OUT + o0 * 32768, nullptr, MIX,
            HB, 1 + l, l, theta, gamma,
            ch_norm_w + l * Dq, ch_norm_b + l * Dq, MIX, nullptr,
            WB + WBE_IN + o1 * 65536, XZ2);

        // ================= channel mamba (fwd+bwd merged) =================
        scan_f<Mq, 32><<<2 * BNq, 256, 0, stream>>>(
            XZ2, dt_proj_w + o1 * 2048, dt_proj_b + o1 * 256,
            A_log + o1 * 4096, D_ssm + o1 * 256,
            conv_w + o1 * 1024, conv_b + o1 * 256,
            WB + WBE_X + o1 * 10240, WB + WBE_X + o2 * 10240, BNq, 1);
        // out_proj ch + fused mix_tok(l+1) + fused tok in_proj(l+1), or Norm2D LN
        if (l < NLq - 1) {
            gemm_mix<1, 1, 1, 4><<<504, 256, 0, stream>>>(
                XZ2, WB + WBE_OUT + o1 * 32768, WB + WBE_OUT + o2 * 32768, MIX,
                HB, 5 + l, l, alpha, beta,
                tok_norm_w + (l + 1) * Dq, tok_norm_b + (l + 1) * Dq, MIX, nullptr,
                WB + WBE_IN + (size_t)((l + 1) * 3) * 65536, XZ2);
        } else {
            gemm_mix<1, 1, 2, 0><<<504, 256, 0, stream>>>(
                XZ2, WB + WBE_OUT + o1 * 32768, WB + WBE_OUT + o2 * 32768, MIX,
                HB, 5 + l, l, nullptr, nullptr,
                n2d_w1, n2d_b1, MIX, nullptr,
                nullptr, nullptr);
        }
    }

    // ---- Norm2D pt2 + head ----
    final_ln2<<<(BMq * Dq + 255) / 256, 256, 0, stream>>>(MIX, n2d_w2, n2d_b2, LNB);
    gemm_k<0, 0, 64><<<dim3(2, 4, 12), 256, 0, stream>>>(
        LNB, Nq * Dq, WB + WBE_HEAD, nullptr, Nq * Dq, nullptr, 0,
        W + OFF_PART, nullptr, PREDq, BMq, PREDq, 672, 672,
        (size_t)BMq * PREDq, 0, 0, 0, nullptr, nullptr, 0, 0, 0, 0, nullptr);
    finalize_kernel<<<(Bq * PREDq * Mq + 255) / 256, 256, 0, stream>>>(
        W + OFF_PART, head_b, W + OFF_MEANS, W + OFF_STDS, out);
}

// Round 12
// 1031.294 us; speedup vs baseline: 1.2571x; 1.2571x over previous
//
#include <hip/hip_runtime.h>
#include <hip/hip_bf16.h>
#include <cstddef>

// ---- problem dims ----
#define Bq    16
#define Lq    512
#define Mq    32
#define PREDq 96
#define Pq    16
#define Sq    8
#define Dq    128
#define NSTq  16
#define DCq   4
#define NLq   4
#define Nq    63
#define DIq   256
#define DTRq  8
#define TOKq  32256   // 512*63 == 1008*32
#define BMq   512
#define BNq   1008

typedef __attribute__((ext_vector_type(8))) short short8;
typedef __attribute__((ext_vector_type(4))) float f32x4;
typedef __attribute__((ext_vector_type(2))) float f32x2;
typedef __hip_bfloat16 bf16;

// ---- workspace layout (float offsets) ----
constexpr size_t HSZB      = (size_t)TOKq * Dq;              // bf16 elements per hist buf
constexpr size_t OFF_MEANS = 0;
constexpr size_t OFF_STDS  = 512;
constexpr size_t OFF_PART  = 50176;                          // 12*49152 fp32
constexpr size_t OFF_HISTB = 640000;                         // 9 hist bufs, bf16
constexpr size_t OFF_MIX   = OFF_HISTB + 9 * (HSZB / 2);     // fp32 TOK*128
constexpr size_t OFF_XD    = OFF_MIX + (size_t)TOKq * 128;   // fp32 TOK*80 (unused)
constexpr size_t OFF_XZ2   = OFF_XD + (size_t)TOKq * 80;     // bf16 TOK*1024
constexpr size_t OFF_UC    = OFF_XZ2 + (size_t)TOKq * 512;   // bf16 TOK*512 (unused)
constexpr size_t OFF_LNB   = OFF_UC + (size_t)TOKq * 256;    // bf16 TOK*128
constexpr size_t OFF_WB    = OFF_LNB + (size_t)TOKq * 64;    // bf16 weights
constexpr size_t WS_FLOATS = OFF_WB + 1038336;
// bf16-element offsets inside WB region (contiguous):
constexpr size_t WBE_IN   = 0;           // 12*512*128 = 786432
constexpr size_t WBE_X    = 786432;      // 12*40*256  = 122880
constexpr size_t WBE_OUT  = 909312;      // 12*128*256 = 393216
constexpr size_t WBE_HEAD = 1302528;     // 96*8064    = 774144
constexpr int    WB_TOTAL = 2076672;

__device__ __forceinline__ float silu_f(float v) { return v / (1.f + __expf(-v)); }

// unpack 2 contiguous bf16 (4B) -> 2 floats
__device__ __forceinline__ f32x2 bfup2(const bf16* p) {
    unsigned int v = *(const unsigned int*)p;
    f32x2 r;
    r.x = __uint_as_float(v << 16);
    r.y = __uint_as_float(v & 0xffff0000u);
    return r;
}
__device__ __forceinline__ void bfpack2(float f0, float f1, bf16* dst) {
    bf16 b0 = __float2bfloat16(f0), b1 = __float2bfloat16(f1);
    unsigned int u = (unsigned int)*(unsigned short*)&b0 |
                     ((unsigned int)*(unsigned short*)&b1 << 16);
    *(unsigned int*)dst = u;
}

// ============ fused fp32 -> bf16 weight conversion ============
__global__ __launch_bounds__(256) void f2b_all(const float* __restrict__ w_in,
                                               const float* __restrict__ w_x,
                                               const float* __restrict__ w_out,
                                               const float* __restrict__ w_head,
                                               bf16* __restrict__ d) {
    int i = blockIdx.x * 256 + threadIdx.x;
    if (i >= WB_TOTAL) return;
    float v;
    if (i < 786432)        v = w_in[i];
    else if (i < 909312)   v = w_x[i - 786432];
    else if (i < 1302528)  v = w_out[i - 909312];
    else                   v = w_head[i - 1302528];
    d[i] = __float2bfloat16(v);
}

// ============ stats ============
__global__ __launch_bounds__(256) void stats_kernel(const float* __restrict__ x,
                                                    float* __restrict__ means,
                                                    float* __restrict__ stds) {
    int bm = blockIdx.x; int b = bm >> 5, m = bm & 31;
    int tid = threadIdx.x;
    float s = 0.f, ss = 0.f;
    for (int l = tid; l < Lq; l += 256) {
        float v = x[((size_t)b * Lq + l) * Mq + m];
        s += v; ss += v * v;
    }
#pragma unroll
    for (int o = 32; o >= 1; o >>= 1) { s += __shfl_xor(s, o); ss += __shfl_xor(ss, o); }
    __shared__ float sh0[4], sh1[4];
    if ((tid & 63) == 0) { sh0[tid >> 6] = s; sh1[tid >> 6] = ss; }
    __syncthreads();
    if (tid == 0) {
        float S  = sh0[0] + sh0[1] + sh0[2] + sh0[3];
        float SS = sh1[0] + sh1[1] + sh1[2] + sh1[3];
        float mean = S * (1.f / (float)Lq);
        float var  = (SS - (float)Lq * mean * mean) * (1.f / (float)(Lq - 1));
        means[bm] = mean;
        stds[bm]  = sqrtf(fmaxf(var, 0.f)) + 1e-5f;
    }
}

// ============ patch embed -> hist[0] (bf16) ============
__global__ __launch_bounds__(128) void patch_embed(const float* __restrict__ x,
                                                   const float* __restrict__ means,
                                                   const float* __restrict__ stds,
                                                   const float* __restrict__ pw,
                                                   const float* __restrict__ pb,
                                                   const float* __restrict__ pos,
                                                   bf16* __restrict__ h) {
    int blk = blockIdx.x;
    int bm = blk / Nq, n = blk - bm * Nq;
    int b = bm >> 5, m = bm & 31;
    int d = threadIdx.x;
    __shared__ float sx[Pq];
    if (d < Pq) {
        int l = n * Sq + d;
        sx[d] = (x[((size_t)b * Lq + l) * Mq + m] - means[bm]) / stds[bm];
    }
    __syncthreads();
    float acc = pb[d];
#pragma unroll
    for (int p = 0; p < Pq; p++) acc += sx[p] * pw[d * Pq + p];
    h[(size_t)blk * Dq + d] = __float2bfloat16(acc + pos[n * Dq + d]);
}

// ============ bf16 MFMA GEMM, templated (in_proj + head) ============
template<int CONVM, int KSKIP, int NT, int MR = 128>
__global__ __launch_bounds__(256) void gemm_k(
        const bf16* __restrict__ A, int lda,
        const bf16* __restrict__ Bw, const bf16* __restrict__ Bw2, int ldb,
        const float* __restrict__ resid, int ldr,
        float* __restrict__ C, bf16* __restrict__ Cb, int ldc,
        int M, int N, int Klen, int kstride, size_t csplit,
        int accum, int rowmap,
        int slen, const float* __restrict__ cw, const float* __restrict__ cb,
        int Mhalf, int ahalfcol, int choff, int gsilu,
        bf16* __restrict__ ucout) {
    constexpr int WR = MR / 4;     // rows per wave
    constexpr int MS = WR / 16;    // 16-row MFMA tiles per wave
    __shared__ __align__(16) short Al[MR * 40];
    __shared__ __align__(16) short Bl[NT * 40];
    int tid = threadIdx.x;
    int wave = tid >> 6, lane = tid & 63;
    int m0 = blockIdx.y * MR, n0 = blockIdx.x * NT;
    int kbase = blockIdx.z * kstride;
    constexpr int NS = NT / 16;
    f32x4 acc[MS][NS];
#pragma unroll
    for (int i = 0; i < MS; i++)
#pragma unroll
        for (int j = 0; j < NS; j++) acc[i][j] = (f32x4){0.f, 0.f, 0.f, 0.f};

    int mlane = lane & 15, koff = (lane >> 4) * 8;
    const uint4 Z4 = {0u, 0u, 0u, 0u};

    {
        int ar = tid >> 1, ah = tid & 1;
        int brr = (NT == 128) ? (tid >> 1) : (tid >> 2);
        int bqh = (NT == 128) ? (tid & 1) : (tid & 3);
        uint4 av0, av1, bv0, bv1;
        av0 = av1 = bv0 = bv1 = Z4;
        auto loadAB = [&](int kk0) {
            int gcol = kk0 + ah * 16;
            if (KSKIP && kk0 >= 256) gcol += 256;
            const bf16* asrc = A + (size_t)(m0 + ar) * lda + gcol;
            av0 = *(const uint4*)asrc;
            av1 = *(const uint4*)(asrc + 8);
            const bf16* bb = Bw;
            if (NT == 128) {
                int bc = kk0 + bqh * 16;
                if (KSKIP && kk0 >= 256) { bb = Bw2; bc -= 256; }
                int gn = n0 + brr;
                if (gn < N) {
                    const bf16* bsrc = bb + (size_t)gn * ldb + bc;
                    bv0 = *(const uint4*)bsrc;
                    bv1 = *(const uint4*)(bsrc + 8);
                } else { bv0 = Z4; bv1 = Z4; }
            } else {
                int bc = kk0 + bqh * 8;
                if (KSKIP && kk0 >= 256) { bb = Bw2; bc -= 256; }
                int gn = n0 + brr;
                bv0 = (gn < N) ? *(const uint4*)(bb + (size_t)gn * ldb + bc) : Z4;
            }
        };
        loadAB(kbase);
        for (int k0 = 0; k0 < Klen; k0 += 32) {
            *(uint4*)&Al[ar * 40 + ah * 16]     = av0;
            *(uint4*)&Al[ar * 40 + ah * 16 + 8] = av1;
            if (NT == 128) {
                *(uint4*)&Bl[brr * 40 + bqh * 16]     = bv0;
                *(uint4*)&Bl[brr * 40 + bqh * 16 + 8] = bv1;
            } else {
                *(uint4*)&Bl[brr * 40 + bqh * 8] = bv0;
            }
            __syncthreads();
            if (k0 + 32 < Klen) loadAB(kbase + k0 + 32);
            short8 afr[MS];
#pragma unroll
            for (int ms = 0; ms < MS; ms++)
                afr[ms] = *(const short8*)&Al[(wave * WR + ms * 16 + mlane) * 40 + koff];
#pragma unroll
            for (int ns = 0; ns < NS; ns++) {
                short8 bfr = *(const short8*)&Bl[(ns * 16 + mlane) * 40 + koff];
#pragma unroll
                for (int ms = 0; ms < MS; ms++)
                    acc[ms][ns] = __builtin_amdgcn_mfma_f32_16x16x32_bf16(afr[ms], bfr, acc[ms][ns], 0, 0, 0);
            }
            __syncthreads();
        }
    }

    float* Cz = C + (size_t)blockIdx.z * csplit;
#pragma unroll
    for (int ms = 0; ms < MS; ms++) {
#pragma unroll
        for (int ns = 0; ns < NS; ns++) {
            int n = n0 + ns * 16 + mlane;
            if (n >= N) continue;
#pragma unroll
            for (int r = 0; r < 4; r++) {
                int m = m0 + wave * WR + ms * 16 + (lane >> 4) * 4 + r;
                int orow = m, ocol = n;
                if (rowmap) {                 // (b*63+nn)*32+mm -> (b*32+mm)*63+nn
                    int bn = m >> 5, mm = m & 31;
                    int b = bn / Nq, nn = bn - b * Nq;
                    orow = (b * Mq + mm) * Nq + nn;
                }
                float v = acc[ms][ns][r];
                if (resid) v += resid[(size_t)orow * ldr + ocol];
                if (Cb) {
                    if (gsilu && ((ocol >> 8) & 1)) v = silu_f(v);   // pre-gate z cols
                    Cb[(size_t)orow * ldc + ocol] = __float2bfloat16(v);
                } else {
                    size_t o = (size_t)orow * ldc + ocol;
                    if (accum) Cz[o] += v; else Cz[o] = v;
                }
            }
        }
    }
}

// ============ out_proj GEMM with fused hist-write + next-mix + LN ============
// MR=64, NT=128 (full 128-col rows per block). KSKIP: K=512 over cols
// {0..255, 512..767} with Bw/Bw2. ROWMAP: m -> (b*32+mm)*63+nn.
// MIXMODE 0: mix_ch(layer l): theta/gamma, LNB transposed.
// MIXMODE 1: mix_tok(layer l+1): alpha/beta rows l+1, LNB linear.
// MIXMODE 2: ln128 (Norm2D pt1): LN(hist) -> mixout fp32 only.
template<int KSKIP, int ROWMAP, int MIXMODE>
__global__ __launch_bounds__(256) void gemm_mix(
        const bf16* __restrict__ A,                 // XZ2, lda=1024
        const bf16* __restrict__ Bw, const bf16* __restrict__ Bw2,  // ldb=256
        const float* __restrict__ resid,            // MIX (pre-LN mamba input)
        bf16* __restrict__ hb, int hwrite, int l,
        const float* __restrict__ mw0, const float* __restrict__ mw1,
        const float* __restrict__ lnw, const float* __restrict__ lnb,
        float* __restrict__ mixout, bf16* __restrict__ lnbout) {
    constexpr int KLEN = KSKIP ? 512 : 256;
    __shared__ __align__(16) short Al[64 * 40];
    __shared__ __align__(16) short Bl[128 * 40];
    int tid = threadIdx.x;
    int wave = tid >> 6, lane = tid & 63;
    int mlane = lane & 15, koff = (lane >> 4) * 8;
    int m0 = blockIdx.x * 64;

    f32x4 acc[8];
#pragma unroll
    for (int j = 0; j < 8; j++) acc[j] = (f32x4){0.f, 0.f, 0.f, 0.f};

    int ar = tid >> 2, ah = tid & 3;        // A: 64 rows, 4 thr/row, 8 cols each
    int br = tid >> 1, bq = tid & 1;        // B: 128 rows, 2 thr/row, 16 cols each
    uint4 av, bv0, bv1;
    auto loadAB = [&](int kk0) {
        int gcol = kk0 + ah * 8;
        if (KSKIP && kk0 >= 256) gcol += 256;
        av = *(const uint4*)(A + (size_t)(m0 + ar) * 1024 + gcol);
        const bf16* bb = Bw;
        int bc = kk0 + bq * 16;
        if (KSKIP && kk0 >= 256) { bb = Bw2; bc -= 256; }
        const bf16* bsrc = bb + (size_t)br * 256 + bc;
        bv0 = *(const uint4*)bsrc;
        bv1 = *(const uint4*)(bsrc + 8);
    };
    loadAB(0);
    for (int k0 = 0; k0 < KLEN; k0 += 32) {
        *(uint4*)&Al[ar * 40 + ah * 8]      = av;
        *(uint4*)&Bl[br * 40 + bq * 16]     = bv0;
        *(uint4*)&Bl[br * 40 + bq * 16 + 8] = bv1;
        __syncthreads();
        if (k0 + 32 < KLEN) loadAB(k0 + 32);
        short8 a = *(const short8*)&Al[(wave * 16 + mlane) * 40 + koff];
#pragma unroll
        for (int ns = 0; ns < 8; ns++) {
            short8 b = *(const short8*)&Bl[(ns * 16 + mlane) * 40 + koff];
            acc[ns] = __builtin_amdgcn_mfma_f32_16x16x32_bf16(a, b, acc[ns], 0, 0, 0);
        }
        __syncthreads();
    }

    // ---- mix softmax weights (uniform across threads) ----
    float w0[5], w1[4];
    int ct = 0, cg = 0;
    if (MIXMODE == 0) {
        ct = l + 2; cg = l + 1;
        float m0v = -1e30f, m1v = -1e30f;
        for (int i = 0; i < ct; i++) { w0[i] = mw0[l * 5 + i]; m0v = fmaxf(m0v, w0[i]); }
        for (int i = 0; i < cg; i++) { w1[i] = mw1[l * 4 + i]; m1v = fmaxf(m1v, w1[i]); }
        float s0 = 0.f, s1 = 0.f;
        for (int i = 0; i < ct; i++) { w0[i] = __expf(w0[i] - m0v); s0 += w0[i]; }
        for (int i = 0; i < cg; i++) { w1[i] = __expf(w1[i] - m1v); s1 += w1[i]; }
        float i0 = 1.f / s0, i1 = 1.f / s1;
        for (int i = 0; i < ct; i++) w0[i] *= i0;
        for (int i = 0; i < cg; i++) w1[i] *= i1;
    } else if (MIXMODE == 1) {
        int lt = l + 1;
        ct = lt + 1; cg = lt + 1;
        float m0v = -1e30f, m1v = -1e30f;
        for (int i = 0; i < ct; i++) {
            w0[i] = mw0[lt * 4 + i]; w1[i] = mw1[lt * 4 + i];
            m0v = fmaxf(m0v, w0[i]); m1v = fmaxf(m1v, w1[i]);
        }
        float s0 = 0.f, s1 = 0.f;
        for (int i = 0; i < ct; i++) {
            w0[i] = __expf(w0[i] - m0v); s0 += w0[i];
            w1[i] = __expf(w1[i] - m1v); s1 += w1[i];
        }
        float i0 = 1.f / s0, i1 = 1.f / s1;
        for (int i = 0; i < ct; i++) { w0[i] *= i0; w1[i] *= i1; }
    }

    // ---- per-row epilogue: hist write + mix + LN ----
#pragma unroll
    for (int r = 0; r < 4; r++) {
        int m = m0 + wave * 16 + (lane >> 4) * 4 + r;
        int orow = m;
        if (ROWMAP) {
            int bn = m >> 5, mm = m & 31;
            int b = bn / Nq, nn = bn - b * Nq;
            orow = (b * Mq + mm) * Nq + nn;
        }
        size_t t128 = (size_t)orow * 128;
        float hv[8];
#pragma unroll
        for (int ns = 0; ns < 8; ns++) {
            int col = ns * 16 + mlane;
            float v = acc[ns][r] + resid[t128 + col];
            bf16 hvb = __float2bfloat16(v);
            hb[(size_t)hwrite * HSZB + t128 + col] = hvb;
            hv[ns] = __bfloat162float(hvb);
        }
        float mixv[8];
        if (MIXMODE == 2) {
#pragma unroll
            for (int ns = 0; ns < 8; ns++) mixv[ns] = hv[ns];
        } else if (MIXMODE == 0) {
#pragma unroll
            for (int ns = 0; ns < 8; ns++) mixv[ns] = 0.f;
            for (int i = 0; i < ct; i++) {
                int bi = (i == 0) ? 0 : i;
                if (bi == hwrite) {
#pragma unroll
                    for (int ns = 0; ns < 8; ns++) mixv[ns] += w0[i] * hv[ns];
                } else {
                    const bf16* yp = hb + (size_t)bi * HSZB + t128;
#pragma unroll
                    for (int ns = 0; ns < 8; ns++)
                        mixv[ns] += w0[i] * __bfloat162float(yp[ns * 16 + mlane]);
                }
            }
            for (int i = 0; i < cg; i++) {
                int bi = (i == 0) ? 0 : 4 + i;
                const bf16* yp = hb + (size_t)bi * HSZB + t128;
#pragma unroll
                for (int ns = 0; ns < 8; ns++)
                    mixv[ns] += w1[i] * __bfloat162float(yp[ns * 16 + mlane]);
            }
        } else {  // MIXMODE 1
#pragma unroll
            for (int ns = 0; ns < 8; ns++) mixv[ns] = 0.f;
            for (int i = 0; i < ct; i++) {
                int bt = (i == 0) ? 0 : i;
                int bc = (i == 0) ? 0 : 4 + i;
                const bf16* ytp = hb + (size_t)bt * HSZB + t128;
                if (bc == hwrite) {
#pragma unroll
                    for (int ns = 0; ns < 8; ns++)
                        mixv[ns] += w0[i] * __bfloat162float(ytp[ns * 16 + mlane]) + w1[i] * hv[ns];
                } else {
                    const bf16* ycp = hb + (size_t)bc * HSZB + t128;
#pragma unroll
                    for (int ns = 0; ns < 8; ns++)
                        mixv[ns] += w0[i] * __bfloat162float(ytp[ns * 16 + mlane]) +
                                    w1[i] * __bfloat162float(ycp[ns * 16 + mlane]);
                }
            }
        }
        // LN row-reduce across the 16-lane group (xor 1,2,4,8)
        float s = 0.f, ss = 0.f;
#pragma unroll
        for (int ns = 0; ns < 8; ns++) { s += mixv[ns]; ss += mixv[ns] * mixv[ns]; }
#pragma unroll
        for (int o = 8; o >= 1; o >>= 1) { s += __shfl_xor(s, o); ss += __shfl_xor(ss, o); }
        float mean = s * (1.f / 128.f);
        float var  = ss * (1.f / 128.f) - mean * mean;
        float rstd = rsqrtf(var + 1e-5f);
        if (MIXMODE == 2) {
#pragma unroll
            for (int ns = 0; ns < 8; ns++) {
                int col = ns * 16 + mlane;
                mixout[t128 + col] = (mixv[ns] - mean) * rstd * lnw[col] + lnb[col];
            }
        } else {
#pragma unroll
            for (int ns = 0; ns < 8; ns++) mixout[t128 + ns * 16 + mlane] = mixv[ns];
            size_t lbase;
            if (MIXMODE == 0) {
                int bm = orow / Nq, nn = orow - bm * Nq, b = bm >> 5, mq = bm & 31;
                lbase = (size_t)((b * Nq + nn) * Mq + mq) * 128;
            } else {
                lbase = t128;
            }
#pragma unroll
            for (int ns = 0; ns < 8; ns++) {
                int col = ns * 16 + mlane;
                lnbout[lbase + col] =
                    __float2bfloat16((mixv[ns] - mean) * rstd * lnw[col] + lnb[col]);
            }
        }
    }
}

// ============ FULLY FUSED mamba core (R7-proven version) ============
template<int SLEN, int ROWS>
__global__ __launch_bounds__(256) void scan_f(bf16* __restrict__ xz2,
                                              const float* __restrict__ dtw,
                                              const float* __restrict__ dtb,
                                              const float* __restrict__ alog,
                                              const float* __restrict__ Dp,
                                              const float* __restrict__ cw,
                                              const float* __restrict__ cb,
                                              const bf16* __restrict__ xw,
                                              const bf16* __restrict__ xw2,
                                              int nb, int dual) {
    constexpr int UST = 264;                      // u row stride in bf16 (528B)
    __shared__ __align__(16) bf16 u_l[ROWS * UST];
    __shared__ __align__(16) float qlds[SLEN * 40];
    int bid = blockIdx.x;
    int half = (dual && bid >= nb) ? 1 : 0;
    int row = bid - half * nb;
    int rev = half;
    int tid = threadIdx.x;
    int d = tid;
    int wave = tid >> 6, lane = tid & 63;
    int mlane = lane & 15, koff = (lane >> 4) * 8;

    size_t xbase = (size_t)row * SLEN * 1024 + (size_t)half * 512 + d;
    size_t base  = xbase;

    float ucur[8], zcur[8];
#pragma unroll
    for (int i = 0; i < 8; i++) {
        int s = rev ? (SLEN - 1 - i) : i;
        zcur[i] = __bfloat162float(xz2[base + (size_t)s * 1024 + 256]);
    }
    const float* al = alog + half * 4096 + d * 16;
    float a0 = -__expf(al[0]);
    bool fast = true;
#pragma unroll
    for (int j = 1; j < 16; j++) {
        float aj = -__expf(al[j]);
        fast = fast && (fabsf(aj - a0 * (float)(j + 1)) < 1e-5f * (float)(j + 1));
    }
    f32x2 dw2[4];
#pragma unroll
    for (int r = 0; r < 4; r++)
        dw2[r] = (f32x2){dtw[half * 2048 + d * 8 + 2 * r], dtw[half * 2048 + d * 8 + 2 * r + 1]};
    float dbv = dtb[half * 256 + d], Dv = Dp[half * 256 + d];

    {
        float c0 = cw[half * 1024 + d * 4 + 0];
        float c1 = cw[half * 1024 + d * 4 + 1];
        float c2 = cw[half * 1024 + d * 4 + 2];
        float c3 = cw[half * 1024 + d * 4 + 3];
        float cbv = cb[half * 256 + d];
        constexpr int NCC = (SLEN + 7) / 8;
        float xc[8], xn[8];
#pragma unroll
        for (int i = 0; i < 8; i++) {
            int st = i < SLEN ? i : SLEN - 1;
            int s = rev ? (SLEN - 1 - st) : st;
            xc[i] = __bfloat162float(xz2[xbase + (size_t)s * 1024]);
        }
        float g1 = 0.f, g2 = 0.f, g3 = 0.f;
        for (int c = 0; c < NCC; c++) {
            if (c + 1 < NCC) {
#pragma unroll
                for (int i = 0; i < 8; i++) {
                    int st = (c + 1) * 8 + i; st = st < SLEN ? st : SLEN - 1;
                    int s = rev ? (SLEN - 1 - st) : st;
                    xn[i] = __bfloat162float(xz2[xbase + (size_t)s * 1024]);
                }
            }
#pragma unroll
            for (int i = 0; i < 8; i++) {
                int st = c * 8 + i;
                if (st < SLEN) {
                    int s = rev ? (SLEN - 1 - st) : st;
                    float cur = xc[i];
                    float ac = cbv;
                    if (st >= 3) ac += c0 * g3;
                    if (st >= 2) ac += c1 * g2;
                    if (st >= 1) ac += c2 * g1;
                    ac += c3 * cur;
                    bf16 ub = __float2bfloat16(silu_f(ac));
                    u_l[s * UST + d] = ub;
                    if (c == 0) ucur[i] = __bfloat162float(ub);
                    g3 = g2; g2 = g1; g1 = cur;
                }
            }
#pragma unroll
            for (int i = 0; i < 8; i++) xc[i] = xn[i];
        }
        for (int s = SLEN; s < ROWS; s++) u_l[s * UST + d] = __float2bfloat16(0.f);
    }
    __syncthreads();

    {
        const bf16* xwp = half ? xw2 : xw;
        constexpr int RT = ROWS / 16;
        constexpr int NTILES = RT * 3;
        const short8 bz = {0, 0, 0, 0, 0, 0, 0, 0};
        for (int tI = wave; tI < NTILES; tI += 4) {
            int tr = tI / 3, tc = tI - tr * 3;
            int gn = tc * 16 + mlane;
            bool okn = gn < 40;
            f32x4 acc = (f32x4){0.f, 0.f, 0.f, 0.f};
#pragma unroll
            for (int kk = 0; kk < 256; kk += 32) {
                short8 a = *(const short8*)&u_l[(tr * 16 + mlane) * UST + kk + koff];
                short8 b = okn ? *(const short8*)(xwp + (size_t)gn * 256 + kk + koff) : bz;
                acc = __builtin_amdgcn_mfma_f32_16x16x32_bf16(a, b, acc, 0, 0, 0);
            }
#pragma unroll
            for (int r = 0; r < 4; r++) {
                int s = tr * 16 + (lane >> 4) * 4 + r;
                if (okn && s < SLEN) qlds[s * 40 + gn] = acc[r];
            }
        }
    }

    f32x2 h2[8];
#pragma unroll
    for (int j = 0; j < 8; j++) h2[j] = (f32x2){0.f, 0.f};
    constexpr int NCH = (SLEN + 7) / 8;
    __syncthreads();

    float unxt[8], znxt[8];
    for (int c = 0; c < NCH; c++) {
        if (c + 1 < NCH) {
#pragma unroll
            for (int i = 0; i < 8; i++) {
                int st = (c + 1) * 8 + i; st = st < SLEN ? st : SLEN - 1;
                int s = rev ? (SLEN - 1 - st) : st;
                unxt[i] = __bfloat162float(u_l[s * UST + d]);
                znxt[i] = __bfloat162float(xz2[base + (size_t)s * 1024 + 256]);
            }
        }
#pragma unroll
        for (int i = 0; i < 8; i++) {
            int st = c * 8 + i;
            if (st < SLEN) {
                int s = rev ? (SLEN - 1 - st) : st;
                const float4* qv = (const float4*)&qlds[s * 40];
                float4 qa = qv[0], qb = qv[1];
                float uc_v = ucur[i];
                f32x2 acc2 = dw2[0] * (f32x2){qa.x, qa.y};
                acc2 += dw2[1] * (f32x2){qa.z, qa.w};
                acc2 += dw2[2] * (f32x2){qb.x, qb.y};
                acc2 += dw2[3] * (f32x2){qb.z, qb.w};
                float dtv = dbv + acc2.x + acc2.y;
                dtv = fmaxf(dtv, 0.f) + __logf(1.f + __expf(-fabsf(dtv)));
                float du = dtv * uc_v;
                float y;
                if (fast) {
                    float p1 = __expf(dtv * a0);
                    float p2 = p1 * p1;
                    f32x2 pp = (f32x2){p2, p2};
                    f32x2 e2[8];
                    e2[0] = (f32x2){p1, p2};
#pragma unroll
                    for (int j = 1; j < 8; j++) e2[j] = e2[j - 1] * pp;
                    f32x2 du2 = (f32x2){du, du};
                    f32x2 y2 = (f32x2){0.f, 0.f};
                    float4 B0 = qv[2], B1 = qv[3], B2 = qv[4], B3 = qv[5];
                    float4 C0 = qv[6], C1 = qv[7], C2 = qv[8], C3 = qv[9];
                    f32x2 bb[8] = {{B0.x, B0.y}, {B0.z, B0.w}, {B1.x, B1.y}, {B1.z, B1.w},
                                   {B2.x, B2.y}, {B2.z, B2.w}, {B3.x, B3.y}, {B3.z, B3.w}};
                    f32x2 cc[8] = {{C0.x, C0.y}, {C0.z, C0.w}, {C1.x, C1.y}, {C1.z, C1.w},
                                   {C2.x, C2.y}, {C2.z, C2.w}, {C3.x, C3.y}, {C3.z, C3.w}};
#pragma unroll
                    for (int j = 0; j < 8; j++) {
                        h2[j] = h2[j] * e2[j] + du2 * bb[j];
                        y2 += h2[j] * cc[j];
                    }
                    y = y2.x + y2.y;
                } else {
                    const float* q = &qlds[s * 40];
                    y = 0.f;
#pragma unroll
                    for (int j = 0; j < 16; j++) {
                        float e = __expf(dtv * (-__expf(al[j])));
                        float hh = h2[j >> 1][j & 1];
                        hh = hh * e + du * q[8 + j];
                        h2[j >> 1][j & 1] = hh;
                        y += hh * q[24 + j];
                    }
                }
                xz2[base + (size_t)s * 1024] =
                    __float2bfloat16((y + uc_v * Dv) * zcur[i]);
            }
        }
#pragma unroll
        for (int i = 0; i < 8; i++) { ucur[i] = unxt[i]; zcur[i] = znxt[i]; }
    }
}

// ============ token mix + LN (standalone, used for layer 0 only) ============
__global__ __launch_bounds__(256) void mix_ln_tok(const bf16* __restrict__ hb,
                                                 float* __restrict__ mixb, bf16* __restrict__ lnb_out,
                                                 const float* __restrict__ alpha,
                                                 const float* __restrict__ beta,
                                                 const float* __restrict__ lnw,
                                                 const float* __restrict__ lnb, int l) {
    int t = blockIdx.x * 4 + (threadIdx.x >> 6), d = threadIdx.x & 63;
    int cnt = l + 1;
    float aw[4], bw[4];
    float amax = -1e30f, bmax = -1e30f;
    for (int i = 0; i < cnt; i++) {
        aw[i] = alpha[l * 4 + i]; bw[i] = beta[l * 4 + i];
        amax = fmaxf(amax, aw[i]); bmax = fmaxf(bmax, bw[i]);
    }
    float as = 0.f, bs = 0.f;
    for (int i = 0; i < cnt; i++) {
        aw[i] = __expf(aw[i] - amax); as += aw[i];
        bw[i] = __expf(bw[i] - bmax); bs += bw[i];
    }
    float ai = 1.f / as, bi = 1.f / bs;
    float v0 = 0.f, v1 = 0.f;
    for (int i = 0; i < cnt; i++) {
        const bf16* yt = hb + (size_t)(i == 0 ? 0 : i) * HSZB + (size_t)t * 128 + 2 * d;
        const bf16* yc = hb + (size_t)(i == 0 ? 0 : 4 + i) * HSZB + (size_t)t * 128 + 2 * d;
        f32x2 vt = bfup2(yt), vc = bfup2(yc);
        float wa = aw[i] * ai, wb = bw[i] * bi;
        v0 += wa * vt.x + wb * vc.x;
        v1 += wa * vt.y + wb * vc.y;
    }
    *(f32x2*)&mixb[(size_t)t * 128 + 2 * d] = (f32x2){v0, v1};
    float s = v0 + v1, ss = v0 * v0 + v1 * v1;
#pragma unroll
    for (int o = 32; o >= 1; o >>= 1) { s += __shfl_xor(s, o); ss += __shfl_xor(ss, o); }
    float mean = s * (1.f / 128.f);
    float var  = ss * (1.f / 128.f) - mean * mean;
    float rstd = rsqrtf(var + 1e-5f);
    f32x2 w2 = *(const f32x2*)&lnw[2 * d];
    f32x2 b2 = *(const f32x2*)&lnb[2 * d];
    bfpack2((v0 - mean) * rstd * w2.x + b2.x,
            (v1 - mean) * rstd * w2.y + b2.y,
            lnb_out + (size_t)t * 128 + 2 * d);
}

// ============ LN over N=63, bf16 out ============
__global__ __launch_bounds__(256) void final_ln2(const float* __restrict__ in,
                                                 const float* __restrict__ w2,
                                                 const float* __restrict__ b2,
                                                 bf16* __restrict__ out) {
    int idx = blockIdx.x * 256 + threadIdx.x;
    if (idx >= BMq * Dq) return;
    int bm = idx >> 7, d = idx & 127;
    float s = 0.f, ss = 0.f;
    for (int n = 0; n < Nq; n++) {
        float v = in[((size_t)bm * Nq + n) * 128 + d];
        s += v; ss += v * v;
    }
    float mean = s * (1.f / (float)Nq);
    float var  = ss * (1.f / (float)Nq) - mean * mean;
    float rstd = rsqrtf(var + 1e-5f);
    for (int n = 0; n < Nq; n++) {
        float v = in[((size_t)bm * Nq + n) * 128 + d];
        out[((size_t)bm * Nq + n) * 128 + d] = __float2bfloat16((v - mean) * rstd * w2[n] + b2[n]);
    }
}

// ============ final: split-K reduce + bias + rescale + transpose ============
__global__ __launch_bounds__(256) void finalize_kernel(const float* __restrict__ part,
                                                       const float* __restrict__ bias,
                                                       const float* __restrict__ means,
                                                       const float* __restrict__ stds,
                                                       float* __restrict__ out) {
    int idx = blockIdx.x * 256 + threadIdx.x;
    if (idx >= Bq * PREDq * Mq) return;
    int b = idx / (PREDq * Mq);
    int r = idx - b * PREDq * Mq;
    int pr = r >> 5, m = r & 31;
    int bm = b * Mq + m;
    float s = bias[pr];
#pragma unroll
    for (int z = 0; z < 12; z++) s += part[(size_t)z * BMq * PREDq + (size_t)bm * PREDq + pr];
    out[idx] = s * stds[bm] + means[bm];
}

extern "C" void kernel_launch(void* const* d_in, const int* in_sizes, int n_in,
                              void* d_out, int out_size, void* d_ws, size_t ws_size,
                              hipStream_t stream) {
    if (ws_size < WS_FLOATS * sizeof(float)) return;

    const float* x          = (const float*)d_in[0];
    const float* patch_w    = (const float*)d_in[1];
    const float* patch_b    = (const float*)d_in[2];
    const float* pos_embed  = (const float*)d_in[3];
    const float* alpha      = (const float*)d_in[4];
    const float* beta       = (const float*)d_in[5];
    const float* theta      = (const float*)d_in[6];
    const float* gamma      = (const float*)d_in[7];
    const float* tok_norm_w = (const float*)d_in[8];
    const float* tok_norm_b = (const float*)d_in[9];
    const float* ch_norm_w  = (const float*)d_in[10];
    const float* ch_norm_b  = (const float*)d_in[11];
    const float* in_proj_w  = (const float*)d_in[12];
    const float* conv_w     = (const float*)d_in[13];
    const float* conv_b     = (const float*)d_in[14];
    const float* x_proj_w   = (const float*)d_in[15];
    const float* dt_proj_w  = (const float*)d_in[16];
    const float* dt_proj_b  = (const float*)d_in[17];
    const float* A_log      = (const float*)d_in[18];
    const float* D_ssm      = (const float*)d_in[19];
    const float* out_proj_w = (const float*)d_in[20];
    const float* n2d_w1     = (const float*)d_in[21];
    const float* n2d_b1     = (const float*)d_in[22];
    const float* n2d_w2     = (const float*)d_in[23];
    const float* n2d_b2     = (const float*)d_in[24];
    const float* head_w     = (const float*)d_in[25];
    const float* head_b     = (const float*)d_in[26];

    float* W   = (float*)d_ws;
    float* out = (float*)d_out;
    bf16* WB   = (bf16*)(W + OFF_WB);
    bf16* HB   = (bf16*)(W + OFF_HISTB);
    bf16* LNB  = (bf16*)(W + OFF_LNB);
    bf16* XZ2  = (bf16*)(W + OFF_XZ2);
    float* MIX = W + OFF_MIX;

    f2b_all<<<(WB_TOTAL + 255) / 256, 256, 0, stream>>>(
        in_proj_w, x_proj_w, out_proj_w, head_w, WB);

    stats_kernel<<<BMq, 256, 0, stream>>>(x, W + OFF_MEANS, W + OFF_STDS);
    patch_embed<<<TOKq, 128, 0, stream>>>(x, W + OFF_MEANS, W + OFF_STDS,
                                          patch_w, patch_b, pos_embed, HB);

    // layer-0 token mix (producer is patch_embed; later mixes are fused)
    mix_ln_tok<<<TOKq / 4, 256, 0, stream>>>(HB, MIX, LNB, alpha, beta,
                                             tok_norm_w, tok_norm_b, 0);

    for (int l = 0; l < NLq; l++) {
        size_t o0 = (size_t)(l * 3 + 0), o1 = (size_t)(l * 3 + 1), o2 = (size_t)(l * 3 + 2);

        // ================= token mamba =================
        gemm_k<0, 0, 128><<<dim3(4, 252, 1), 256, 0, stream>>>(
            LNB, 128, WB + WBE_IN + o0 * 65536, nullptr, 128, nullptr, 0,
            nullptr, XZ2, 1024, TOKq, 512, 128, 0, 0, 0, 0,
            0, nullptr, nullptr, 0, 0, 0, 1, nullptr);
        scan_f<Nq, 64><<<BMq, 256, 0, stream>>>(
            XZ2, dt_proj_w + o0 * 2048, dt_proj_b + o0 * 256,
            A_log + o0 * 4096, D_ssm + o0 * 256,
            conv_w + o0 * 1024, conv_b + o0 * 256,
            WB + WBE_X + o0 * 10240, nullptr, BMq, 0);
        // out_proj tok + fused mix_ch(l) + LN
        gemm_mix<0, 0, 0><<<504, 256, 0, stream>>>(
            XZ2, WB + WBE_OUT + o0 * 32768, nullptr, MIX,
            HB, 1 + l, l, theta, gamma,
            ch_norm_w + l * Dq, ch_norm_b + l * Dq, MIX, LNB);

        // ================= channel mamba (fwd+bwd merged) =================
        gemm_k<0, 0, 128><<<dim3(8, 252, 1), 256, 0, stream>>>(
            LNB, 128, WB + WBE_IN + o1 * 65536, nullptr, 128, nullptr, 0,
            nullptr, XZ2, 1024, TOKq, 1024, 128, 0, 0, 0, 0,
            0, nullptr, nullptr, 0, 0, 0, 1, nullptr);
        scan_f<Mq, 32><<<2 * BNq, 256, 0, stream>>>(
            XZ2, dt_proj_w + o1 * 2048, dt_proj_b + o1 * 256,
            A_log + o1 * 4096, D_ssm + o1 * 256,
            conv_w + o1 * 1024, conv_b + o1 * 256,
            WB + WBE_X + o1 * 10240, WB + WBE_X + o2 * 10240, BNq, 1);
        // out_proj ch + fused mix_tok(l+1) (or Norm2D LN for last layer)
        if (l < NLq - 1) {
            gemm_mix<1, 1, 1><<<504, 256, 0, stream>>>(
                XZ2, WB + WBE_OUT + o1 * 32768, WB + WBE_OUT + o2 * 32768, MIX,
                HB, 5 + l, l, alpha, beta,
                tok_norm_w + (l + 1) * Dq, tok_norm_b + (l + 1) * Dq, MIX, LNB);
        } else {
            gemm_mix<1, 1, 2><<<504, 256, 0, stream>>>(
                XZ2, WB + WBE_OUT + o1 * 32768, WB + WBE_OUT + o2 * 32768, MIX,
                HB, 5 + l, l, nullptr, nullptr,
                n2d_w1, n2d_b1, MIX, nullptr);
        }
    }

    // ---- Norm2D pt2 + head ----
    final_ln2<<<(BMq * Dq + 255) / 256, 256, 0, stream>>>(MIX, n2d_w2, n2d_b2, LNB);
    gemm_k<0, 0, 64><<<dim3(2, 4, 12), 256, 0, stream>>>(
        LNB, Nq * Dq, WB + WBE_HEAD, nullptr, Nq * Dq, nullptr, 0,
        W + OFF_PART, nullptr, PREDq, BMq, PREDq, 672, 672,
        (size_t)BMq * PREDq, 0, 0, 0, nullptr, nullptr, 0, 0, 0, 0, nullptr);
    finalize_kernel<<<(Bq * PREDq * Mq + 255) / 256, 256, 0, stream>>>(
        W + OFF_PART, head_b, W + OFF_MEANS, W + OFF_STDS, out);
}

// Round 15
// 980.674 us; speedup vs baseline: 1.3220x; 1.0516x over previous
//
#include <hip/hip_runtime.h>
#include <hip/hip_bf16.h>
#include <cstddef>

// ---- problem dims ----
#define Bq    16
#define Lq    512
#define Mq    32
#define PREDq 96
#define Pq    16
#define Sq    8
#define Dq    128
#define NSTq  16
#define DCq   4
#define NLq   4
#define Nq    63
#define DIq   256
#define DTRq  8
#define TOKq  32256   // 512*63 == 1008*32
#define BMq   512
#define BNq   1008

typedef __attribute__((ext_vector_type(8))) short short8;
typedef __attribute__((ext_vector_type(4))) float f32x4;
typedef __attribute__((ext_vector_type(2))) float f32x2;
typedef __hip_bfloat16 bf16;

// ---- workspace layout (float offsets) ----
constexpr size_t HSZB      = (size_t)TOKq * Dq;              // bf16 elements per hist buf
constexpr size_t OFF_MEANS = 0;
constexpr size_t OFF_STDS  = 512;
constexpr size_t OFF_PART  = 50176;                          // 12*49152 fp32
constexpr size_t OFF_HISTB = 640000;                         // 9 hist bufs, bf16
constexpr size_t OFF_MIX   = OFF_HISTB + 9 * (HSZB / 2);     // fp32 TOK*128
constexpr size_t OFF_XD    = OFF_MIX + (size_t)TOKq * 128;   // fp32 TOK*80 (unused)
constexpr size_t OFF_XZ2   = OFF_XD + (size_t)TOKq * 80;     // bf16 TOK*1024
constexpr size_t OFF_UC    = OFF_XZ2 + (size_t)TOKq * 512;   // bf16 TOK*512 (unused)
constexpr size_t OFF_LNB   = OFF_UC + (size_t)TOKq * 256;    // bf16 TOK*128
constexpr size_t OFF_WB    = OFF_LNB + (size_t)TOKq * 64;    // bf16 weights
constexpr size_t WS_FLOATS = OFF_WB + 1038336;
// bf16-element offsets inside WB region (contiguous):
constexpr size_t WBE_IN   = 0;           // 12*512*128 = 786432
constexpr size_t WBE_X    = 786432;      // 12*40*256  = 122880
constexpr size_t WBE_OUT  = 909312;      // 12*128*256 = 393216
constexpr size_t WBE_HEAD = 1302528;     // 96*8064    = 774144
constexpr int    WB_TOTAL = 2076672;

__device__ __forceinline__ float silu_f(float v) { return v / (1.f + __expf(-v)); }

// unpack 2 contiguous bf16 (4B) -> 2 floats
__device__ __forceinline__ f32x2 bfup2(const bf16* p) {
    unsigned int v = *(const unsigned int*)p;
    f32x2 r;
    r.x = __uint_as_float(v << 16);
    r.y = __uint_as_float(v & 0xffff0000u);
    return r;
}
__device__ __forceinline__ void bfpack2(float f0, float f1, bf16* dst) {
    bf16 b0 = __float2bfloat16(f0), b1 = __float2bfloat16(f1);
    unsigned int u = (unsigned int)*(unsigned short*)&b0 |
                     ((unsigned int)*(unsigned short*)&b1 << 16);
    *(unsigned int*)dst = u;
}

// ============ fused fp32 -> bf16 weight conversion ============
__global__ __launch_bounds__(256) void f2b_all(const float* __restrict__ w_in,
                                               const float* __restrict__ w_x,
                                               const float* __restrict__ w_out,
                                               const float* __restrict__ w_head,
                                               bf16* __restrict__ d) {
    int i = blockIdx.x * 256 + threadIdx.x;
    if (i >= WB_TOTAL) return;
    float v;
    if (i < 786432)        v = w_in[i];
    else if (i < 909312)   v = w_x[i - 786432];
    else if (i < 1302528)  v = w_out[i - 909312];
    else                   v = w_head[i - 1302528];
    d[i] = __float2bfloat16(v);
}

// ============ stats ============
__global__ __launch_bounds__(256) void stats_kernel(const float* __restrict__ x,
                                                    float* __restrict__ means,
                                                    float* __restrict__ stds) {
    int bm = blockIdx.x; int b = bm >> 5, m = bm & 31;
    int tid = threadIdx.x;
    float s = 0.f, ss = 0.f;
    for (int l = tid; l < Lq; l += 256) {
        float v = x[((size_t)b * Lq + l) * Mq + m];
        s += v; ss += v * v;
    }
#pragma unroll
    for (int o = 32; o >= 1; o >>= 1) { s += __shfl_xor(s, o); ss += __shfl_xor(ss, o); }
    __shared__ float sh0[4], sh1[4];
    if ((tid & 63) == 0) { sh0[tid >> 6] = s; sh1[tid >> 6] = ss; }
    __syncthreads();
    if (tid == 0) {
        float S  = sh0[0] + sh0[1] + sh0[2] + sh0[3];
        float SS = sh1[0] + sh1[1] + sh1[2] + sh1[3];
        float mean = S * (1.f / (float)Lq);
        float var  = (SS - (float)Lq * mean * mean) * (1.f / (float)(Lq - 1));
        means[bm] = mean;
        stds[bm]  = sqrtf(fmaxf(var, 0.f)) + 1e-5f;
    }
}

// ============ patch embed -> hist[0] (bf16) ============
__global__ __launch_bounds__(128) void patch_embed(const float* __restrict__ x,
                                                   const float* __restrict__ means,
                                                   const float* __restrict__ stds,
                                                   const float* __restrict__ pw,
                                                   const float* __restrict__ pb,
                                                   const float* __restrict__ pos,
                                                   bf16* __restrict__ h) {
    int blk = blockIdx.x;
    int bm = blk / Nq, n = blk - bm * Nq;
    int b = bm >> 5, m = bm & 31;
    int d = threadIdx.x;
    __shared__ float sx[Pq];
    if (d < Pq) {
        int l = n * Sq + d;
        sx[d] = (x[((size_t)b * Lq + l) * Mq + m] - means[bm]) / stds[bm];
    }
    __syncthreads();
    float acc = pb[d];
#pragma unroll
    for (int p = 0; p < Pq; p++) acc += sx[p] * pw[d * Pq + p];
    h[(size_t)blk * Dq + d] = __float2bfloat16(acc + pos[n * Dq + d]);
}

// ============ K=128 in_proj GEMM: full-K single-stage, ONE barrier ============
// A: LNB [TOK][128], B: in_proj weights [N][128] (rows contiguous; for the
// channel case o1|o2 halves are adjacent so one pointer covers N=1024).
// Output: XZ2 [TOK][1024] bf16 with silu applied to z columns ((col>>8)&1).
// MFMA accumulation is k-ascending per output element == old gemm_k order
// (bit-identical results). MR=64, NT=128; grid = (N/128, TOK/64).
// NOTE: one uint4 = 8 bf16 elements -> element offsets step by 8 (R13 bugfix).
__global__ __launch_bounds__(256) void gemm_in(const bf16* __restrict__ A,
                                               const bf16* __restrict__ Bw,
                                               bf16* __restrict__ Cb) {
    __shared__ __align__(16) short Al[64 * 136];
    __shared__ __align__(16) short Bl[128 * 136];
    int tid = threadIdx.x;
    int wave = tid >> 6, lane = tid & 63;
    int mlane = lane & 15, koff = (lane >> 4) * 8;
    int m0 = blockIdx.y * 64, n0 = blockIdx.x * 128;

    {
        int ar = tid >> 2, ah = tid & 3;           // 64 rows, 4 thr/row, 32 cols each
        const bf16* asrc = A + (size_t)(m0 + ar) * 128 + ah * 32;
        uint4 a[4];
#pragma unroll
        for (int i = 0; i < 4; i++) a[i] = *(const uint4*)(asrc + i * 8);
        int br = tid >> 1, bq = tid & 1;           // 128 rows, 2 thr/row, 64 cols each
        const bf16* bsrc = Bw + (size_t)(n0 + br) * 128 + bq * 64;
        uint4 b[8];
#pragma unroll
        for (int i = 0; i < 8; i++) b[i] = *(const uint4*)(bsrc + i * 8);
#pragma unroll
        for (int i = 0; i < 4; i++) *(uint4*)&Al[ar * 136 + ah * 32 + i * 8] = a[i];
#pragma unroll
        for (int i = 0; i < 8; i++) *(uint4*)&Bl[br * 136 + bq * 64 + i * 8] = b[i];
    }
    __syncthreads();

    f32x4 acc[8];
#pragma unroll
    for (int j = 0; j < 8; j++) acc[j] = (f32x4){0.f, 0.f, 0.f, 0.f};
#pragma unroll
    for (int kI = 0; kI < 4; kI++) {
        short8 a = *(const short8*)&Al[(wave * 16 + mlane) * 136 + kI * 32 + koff];
#pragma unroll
        for (int ns = 0; ns < 8; ns++) {
            short8 b = *(const short8*)&Bl[(ns * 16 + mlane) * 136 + kI * 32 + koff];
            acc[ns] = __builtin_amdgcn_mfma_f32_16x16x32_bf16(a, b, acc[ns], 0, 0, 0);
        }
    }

#pragma unroll
    for (int ns = 0; ns < 8; ns++) {
        int col = n0 + ns * 16 + mlane;
        bool zc = (col >> 8) & 1;
#pragma unroll
        for (int r = 0; r < 4; r++) {
            int m = m0 + wave * 16 + (lane >> 4) * 4 + r;
            float v = acc[ns][r];
            if (zc) v = silu_f(v);                 // pre-gate z cols
            Cb[(size_t)m * 1024 + col] = __float2bfloat16(v);
        }
    }
}

// ============ bf16 MFMA GEMM, templated (head only now) ============
template<int CONVM, int KSKIP, int NT, int MR = 128>
__global__ __launch_bounds__(256) void gemm_k(
        const bf16* __restrict__ A, int lda,
        const bf16* __restrict__ Bw, const bf16* __restrict__ Bw2, int ldb,
        const float* __restrict__ resid, int ldr,
        float* __restrict__ C, bf16* __restrict__ Cb, int ldc,
        int M, int N, int Klen, int kstride, size_t csplit,
        int accum, int rowmap,
        int slen, const float* __restrict__ cw, const float* __restrict__ cb,
        int Mhalf, int ahalfcol, int choff, int gsilu,
        bf16* __restrict__ ucout) {
    constexpr int WR = MR / 4;     // rows per wave
    constexpr int MS = WR / 16;    // 16-row MFMA tiles per wave
    __shared__ __align__(16) short Al[MR * 40];
    __shared__ __align__(16) short Bl[NT * 40];
    int tid = threadIdx.x;
    int wave = tid >> 6, lane = tid & 63;
    int m0 = blockIdx.y * MR, n0 = blockIdx.x * NT;
    int kbase = blockIdx.z * kstride;
    constexpr int NS = NT / 16;
    f32x4 acc[MS][NS];
#pragma unroll
    for (int i = 0; i < MS; i++)
#pragma unroll
        for (int j = 0; j < NS; j++) acc[i][j] = (f32x4){0.f, 0.f, 0.f, 0.f};

    int mlane = lane & 15, koff = (lane >> 4) * 8;
    const uint4 Z4 = {0u, 0u, 0u, 0u};

    {
        int ar = tid >> 1, ah = tid & 1;
        int brr = (NT == 128) ? (tid >> 1) : (tid >> 2);
        int bqh = (NT == 128) ? (tid & 1) : (tid & 3);
        uint4 av0, av1, bv0, bv1;
        av0 = av1 = bv0 = bv1 = Z4;
        auto loadAB = [&](int kk0) {
            int gcol = kk0 + ah * 16;
            if (KSKIP && kk0 >= 256) gcol += 256;
            const bf16* asrc = A + (size_t)(m0 + ar) * lda + gcol;
            av0 = *(const uint4*)asrc;
            av1 = *(const uint4*)(asrc + 8);
            const bf16* bb = Bw;
            if (NT == 128) {
                int bc = kk0 + bqh * 16;
                if (KSKIP && kk0 >= 256) { bb = Bw2; bc -= 256; }
                int gn = n0 + brr;
                if (gn < N) {
                    const bf16* bsrc = bb + (size_t)gn * ldb + bc;
                    bv0 = *(const uint4*)bsrc;
                    bv1 = *(const uint4*)(bsrc + 8);
                } else { bv0 = Z4; bv1 = Z4; }
            } else {
                int bc = kk0 + bqh * 8;
                if (KSKIP && kk0 >= 256) { bb = Bw2; bc -= 256; }
                int gn = n0 + brr;
                bv0 = (gn < N) ? *(const uint4*)(bb + (size_t)gn * ldb + bc) : Z4;
            }
        };
        loadAB(kbase);
        for (int k0 = 0; k0 < Klen; k0 += 32) {
            *(uint4*)&Al[ar * 40 + ah * 16]     = av0;
            *(uint4*)&Al[ar * 40 + ah * 16 + 8] = av1;
            if (NT == 128) {
                *(uint4*)&Bl[brr * 40 + bqh * 16]     = bv0;
                *(uint4*)&Bl[brr * 40 + bqh * 16 + 8] = bv1;
            } else {
                *(uint4*)&Bl[brr * 40 + bqh * 8] = bv0;
            }
            __syncthreads();
            if (k0 + 32 < Klen) loadAB(kbase + k0 + 32);
            short8 afr[MS];
#pragma unroll
            for (int ms = 0; ms < MS; ms++)
                afr[ms] = *(const short8*)&Al[(wave * WR + ms * 16 + mlane) * 40 + koff];
#pragma unroll
            for (int ns = 0; ns < NS; ns++) {
                short8 bfr = *(const short8*)&Bl[(ns * 16 + mlane) * 40 + koff];
#pragma unroll
                for (int ms = 0; ms < MS; ms++)
                    acc[ms][ns] = __builtin_amdgcn_mfma_f32_16x16x32_bf16(afr[ms], bfr, acc[ms][ns], 0, 0, 0);
            }
            __syncthreads();
        }
    }

    float* Cz = C + (size_t)blockIdx.z * csplit;
#pragma unroll
    for (int ms = 0; ms < MS; ms++) {
#pragma unroll
        for (int ns = 0; ns < NS; ns++) {
            int n = n0 + ns * 16 + mlane;
            if (n >= N) continue;
#pragma unroll
            for (int r = 0; r < 4; r++) {
                int m = m0 + wave * WR + ms * 16 + (lane >> 4) * 4 + r;
                int orow = m, ocol = n;
                if (rowmap) {                 // (b*63+nn)*32+mm -> (b*32+mm)*63+nn
                    int bn = m >> 5, mm = m & 31;
                    int b = bn / Nq, nn = bn - b * Nq;
                    orow = (b * Mq + mm) * Nq + nn;
                }
                float v = acc[ms][ns][r];
                if (resid) v += resid[(size_t)orow * ldr + ocol];
                if (Cb) {
                    if (gsilu && ((ocol >> 8) & 1)) v = silu_f(v);   // pre-gate z cols
                    Cb[(size_t)orow * ldc + ocol] = __float2bfloat16(v);
                } else {
                    size_t o = (size_t)orow * ldc + ocol;
                    if (accum) Cz[o] += v; else Cz[o] = v;
                }
            }
        }
    }
}

// ============ out_proj GEMM with fused hist-write + next-mix + LN ============
// MR=64, NT=128 (full 128-col rows per block). KSKIP: K=512 over cols
// {0..255, 512..767} with Bw/Bw2. ROWMAP: m -> (b*32+mm)*63+nn.
// MIXMODE 0: mix_ch(layer l): theta/gamma, LNB transposed.
// MIXMODE 1: mix_tok(layer l+1): alpha/beta rows l+1, LNB linear.
// MIXMODE 2: ln128 (Norm2D pt1): LN(hist) -> mixout fp32 only.
template<int KSKIP, int ROWMAP, int MIXMODE>
__global__ __launch_bounds__(256) void gemm_mix(
        const bf16* __restrict__ A,                 // XZ2, lda=1024
        const bf16* __restrict__ Bw, const bf16* __restrict__ Bw2,  // ldb=256
        const float* __restrict__ resid,            // MIX (pre-LN mamba input)
        bf16* __restrict__ hb, int hwrite, int l,
        const float* __restrict__ mw0, const float* __restrict__ mw1,
        const float* __restrict__ lnw, const float* __restrict__ lnb,
        float* __restrict__ mixout, bf16* __restrict__ lnbout) {
    constexpr int KLEN = KSKIP ? 512 : 256;
    __shared__ __align__(16) short Al[64 * 40];
    __shared__ __align__(16) short Bl[128 * 40];
    int tid = threadIdx.x;
    int wave = tid >> 6, lane = tid & 63;
    int mlane = lane & 15, koff = (lane >> 4) * 8;
    int m0 = blockIdx.x * 64;

    f32x4 acc[8];
#pragma unroll
    for (int j = 0; j < 8; j++) acc[j] = (f32x4){0.f, 0.f, 0.f, 0.f};

    int ar = tid >> 2, ah = tid & 3;        // A: 64 rows, 4 thr/row, 8 cols each
    int br = tid >> 1, bq = tid & 1;        // B: 128 rows, 2 thr/row, 16 cols each
    uint4 av, bv0, bv1;
    auto loadAB = [&](int kk0) {
        int gcol = kk0 + ah * 8;
        if (KSKIP && kk0 >= 256) gcol += 256;
        av = *(const uint4*)(A + (size_t)(m0 + ar) * 1024 + gcol);
        const bf16* bb = Bw;
        int bc = kk0 + bq * 16;
        if (KSKIP && kk0 >= 256) { bb = Bw2; bc -= 256; }
        const bf16* bsrc = bb + (size_t)br * 256 + bc;
        bv0 = *(const uint4*)bsrc;
        bv1 = *(const uint4*)(bsrc + 8);
    };
    loadAB(0);
    for (int k0 = 0; k0 < KLEN; k0 += 32) {
        *(uint4*)&Al[ar * 40 + ah * 8]      = av;
        *(uint4*)&Bl[br * 40 + bq * 16]     = bv0;
        *(uint4*)&Bl[br * 40 + bq * 16 + 8] = bv1;
        __syncthreads();
        if (k0 + 32 < KLEN) loadAB(k0 + 32);
        short8 a = *(const short8*)&Al[(wave * 16 + mlane) * 40 + koff];
#pragma unroll
        for (int ns = 0; ns < 8; ns++) {
            short8 b = *(const short8*)&Bl[(ns * 16 + mlane) * 40 + koff];
            acc[ns] = __builtin_amdgcn_mfma_f32_16x16x32_bf16(a, b, acc[ns], 0, 0, 0);
        }
        __syncthreads();
    }

    // ---- mix softmax weights (uniform across threads) ----
    float w0[5], w1[4];
    int ct = 0, cg = 0;
    if (MIXMODE == 0) {
        ct = l + 2; cg = l + 1;
        float m0v = -1e30f, m1v = -1e30f;
        for (int i = 0; i < ct; i++) { w0[i] = mw0[l * 5 + i]; m0v = fmaxf(m0v, w0[i]); }
        for (int i = 0; i < cg; i++) { w1[i] = mw1[l * 4 + i]; m1v = fmaxf(m1v, w1[i]); }
        float s0 = 0.f, s1 = 0.f;
        for (int i = 0; i < ct; i++) { w0[i] = __expf(w0[i] - m0v); s0 += w0[i]; }
        for (int i = 0; i < cg; i++) { w1[i] = __expf(w1[i] - m1v); s1 += w1[i]; }
        float i0 = 1.f / s0, i1 = 1.f / s1;
        for (int i = 0; i < ct; i++) w0[i] *= i0;
        for (int i = 0; i < cg; i++) w1[i] *= i1;
    } else if (MIXMODE == 1) {
        int lt = l + 1;
        ct = lt + 1; cg = lt + 1;
        float m0v = -1e30f, m1v = -1e30f;
        for (int i = 0; i < ct; i++) {
            w0[i] = mw0[lt * 4 + i]; w1[i] = mw1[lt * 4 + i];
            m0v = fmaxf(m0v, w0[i]); m1v = fmaxf(m1v, w1[i]);
        }
        float s0 = 0.f, s1 = 0.f;
        for (int i = 0; i < ct; i++) {
            w0[i] = __expf(w0[i] - m0v); s0 += w0[i];
            w1[i] = __expf(w1[i] - m1v); s1 += w1[i];
        }
        float i0 = 1.f / s0, i1 = 1.f / s1;
        for (int i = 0; i < ct; i++) { w0[i] *= i0; w1[i] *= i1; }
    }

    // ---- per-row epilogue: hist write + mix + LN ----
#pragma unroll
    for (int r = 0; r < 4; r++) {
        int m = m0 + wave * 16 + (lane >> 4) * 4 + r;
        int orow = m;
        if (ROWMAP) {
            int bn = m >> 5, mm = m & 31;
            int b = bn / Nq, nn = bn - b * Nq;
            orow = (b * Mq + mm) * Nq + nn;
        }
        size_t t128 = (size_t)orow * 128;
        float hv[8];
#pragma unroll
        for (int ns = 0; ns < 8; ns++) {
            int col = ns * 16 + mlane;
            float v = acc[ns][r] + resid[t128 + col];
            bf16 hvb = __float2bfloat16(v);
            hb[(size_t)hwrite * HSZB + t128 + col] = hvb;
            hv[ns] = __bfloat162float(hvb);
        }
        float mixv[8];
        if (MIXMODE == 2) {
#pragma unroll
            for (int ns = 0; ns < 8; ns++) mixv[ns] = hv[ns];
        } else if (MIXMODE == 0) {
#pragma unroll
            for (int ns = 0; ns < 8; ns++) mixv[ns] = 0.f;
            for (int i = 0; i < ct; i++) {
                int bi = (i == 0) ? 0 : i;
                if (bi == hwrite) {
#pragma unroll
                    for (int ns = 0; ns < 8; ns++) mixv[ns] += w0[i] * hv[ns];
                } else {
                    const bf16* yp = hb + (size_t)bi * HSZB + t128;
#pragma unroll
                    for (int ns = 0; ns < 8; ns++)
                        mixv[ns] += w0[i] * __bfloat162float(yp[ns * 16 + mlane]);
                }
            }
            for (int i = 0; i < cg; i++) {
                int bi = (i == 0) ? 0 : 4 + i;
                const bf16* yp = hb + (size_t)bi * HSZB + t128;
#pragma unroll
                for (int ns = 0; ns < 8; ns++)
                    mixv[ns] += w1[i] * __bfloat162float(yp[ns * 16 + mlane]);
            }
        } else {  // MIXMODE 1
#pragma unroll
            for (int ns = 0; ns < 8; ns++) mixv[ns] = 0.f;
            for (int i = 0; i < ct; i++) {
                int bt = (i == 0) ? 0 : i;
                int bc = (i == 0) ? 0 : 4 + i;
                const bf16* ytp = hb + (size_t)bt * HSZB + t128;
                if (bc == hwrite) {
#pragma unroll
                    for (int ns = 0; ns < 8; ns++)
                        mixv[ns] += w0[i] * __bfloat162float(ytp[ns * 16 + mlane]) + w1[i] * hv[ns];
                } else {
                    const bf16* ycp = hb + (size_t)bc * HSZB + t128;
#pragma unroll
                    for (int ns = 0; ns < 8; ns++)
                        mixv[ns] += w0[i] * __bfloat162float(ytp[ns * 16 + mlane]) +
                                    w1[i] * __bfloat162float(ycp[ns * 16 + mlane]);
                }
            }
        }
        // LN row-reduce across the 16-lane group (xor 1,2,4,8)
        float s = 0.f, ss = 0.f;
#pragma unroll
        for (int ns = 0; ns < 8; ns++) { s += mixv[ns]; ss += mixv[ns] * mixv[ns]; }
#pragma unroll
        for (int o = 8; o >= 1; o >>= 1) { s += __shfl_xor(s, o); ss += __shfl_xor(ss, o); }
        float mean = s * (1.f / 128.f);
        float var  = ss * (1.f / 128.f) - mean * mean;
        float rstd = rsqrtf(var + 1e-5f);
        if (MIXMODE == 2) {
#pragma unroll
            for (int ns = 0; ns < 8; ns++) {
                int col = ns * 16 + mlane;
                mixout[t128 + col] = (mixv[ns] - mean) * rstd * lnw[col] + lnb[col];
            }
        } else {
#pragma unroll
            for (int ns = 0; ns < 8; ns++) mixout[t128 + ns * 16 + mlane] = mixv[ns];
            size_t lbase;
            if (MIXMODE == 0) {
                int bm = orow / Nq, nn = orow - bm * Nq, b = bm >> 5, mq = bm & 31;
                lbase = (size_t)((b * Nq + nn) * Mq + mq) * 128;
            } else {
                lbase = t128;
            }
#pragma unroll
            for (int ns = 0; ns < 8; ns++) {
                int col = ns * 16 + mlane;
                lnbout[lbase + col] =
                    __float2bfloat16((mixv[ns] - mean) * rstd * lnw[col] + lnb[col]);
            }
        }
    }
}

// ============ FULLY FUSED mamba core (R7-proven version) ============
template<int SLEN, int ROWS>
__global__ __launch_bounds__(256) void scan_f(bf16* __restrict__ xz2,
                                              const float* __restrict__ dtw,
                                              const float* __restrict__ dtb,
                                              const float* __restrict__ alog,
                                              const float* __restrict__ Dp,
                                              const float* __restrict__ cw,
                                              const float* __restrict__ cb,
                                              const bf16* __restrict__ xw,
                                              const bf16* __restrict__ xw2,
                                              int nb, int dual) {
    constexpr int UST = 264;                      // u row stride in bf16 (528B)
    __shared__ __align__(16) bf16 u_l[ROWS * UST];
    __shared__ __align__(16) float qlds[SLEN * 40];
    int bid = blockIdx.x;
    int half = (dual && bid >= nb) ? 1 : 0;
    int row = bid - half * nb;
    int rev = half;
    int tid = threadIdx.x;
    int d = tid;
    int wave = tid >> 6, lane = tid & 63;
    int mlane = lane & 15, koff = (lane >> 4) * 8;

    size_t xbase = (size_t)row * SLEN * 1024 + (size_t)half * 512 + d;
    size_t base  = xbase;

    float ucur[8], zcur[8];
#pragma unroll
    for (int i = 0; i < 8; i++) {
        int s = rev ? (SLEN - 1 - i) : i;
        zcur[i] = __bfloat162float(xz2[base + (size_t)s * 1024 + 256]);
    }
    const float* al = alog + half * 4096 + d * 16;
    float a0 = -__expf(al[0]);
    bool fast = true;
#pragma unroll
    for (int j = 1; j < 16; j++) {
        float aj = -__expf(al[j]);
        fast = fast && (fabsf(aj - a0 * (float)(j + 1)) < 1e-5f * (float)(j + 1));
    }
    f32x2 dw2[4];
#pragma unroll
    for (int r = 0; r < 4; r++)
        dw2[r] = (f32x2){dtw[half * 2048 + d * 8 + 2 * r], dtw[half * 2048 + d * 8 + 2 * r + 1]};
    float dbv = dtb[half * 256 + d], Dv = Dp[half * 256 + d];

    {
        float c0 = cw[half * 1024 + d * 4 + 0];
        float c1 = cw[half * 1024 + d * 4 + 1];
        float c2 = cw[half * 1024 + d * 4 + 2];
        float c3 = cw[half * 1024 + d * 4 + 3];
        float cbv = cb[half * 256 + d];
        constexpr int NCC = (SLEN + 7) / 8;
        float xc[8], xn[8];
#pragma unroll
        for (int i = 0; i < 8; i++) {
            int st = i < SLEN ? i : SLEN - 1;
            int s = rev ? (SLEN - 1 - st) : st;
            xc[i] = __bfloat162float(xz2[xbase + (size_t)s * 1024]);
        }
        float g1 = 0.f, g2 = 0.f, g3 = 0.f;
        for (int c = 0; c < NCC; c++) {
            if (c + 1 < NCC) {
#pragma unroll
                for (int i = 0; i < 8; i++) {
                    int st = (c + 1) * 8 + i; st = st < SLEN ? st : SLEN - 1;
                    int s = rev ? (SLEN - 1 - st) : st;
                    xn[i] = __bfloat162float(xz2[xbase + (size_t)s * 1024]);
                }
            }
#pragma unroll
            for (int i = 0; i < 8; i++) {
                int st = c * 8 + i;
                if (st < SLEN) {
                    int s = rev ? (SLEN - 1 - st) : st;
                    float cur = xc[i];
                    float ac = cbv;
                    if (st >= 3) ac += c0 * g3;
                    if (st >= 2) ac += c1 * g2;
                    if (st >= 1) ac += c2 * g1;
                    ac += c3 * cur;
                    bf16 ub = __float2bfloat16(silu_f(ac));
                    u_l[s * UST + d] = ub;
                    if (c == 0) ucur[i] = __bfloat162float(ub);
                    g3 = g2; g2 = g1; g1 = cur;
                }
            }
#pragma unroll
            for (int i = 0; i < 8; i++) xc[i] = xn[i];
        }
        for (int s = SLEN; s < ROWS; s++) u_l[s * UST + d] = __float2bfloat16(0.f);
    }
    __syncthreads();

    {
        const bf16* xwp = half ? xw2 : xw;
        constexpr int RT = ROWS / 16;
        constexpr int NTILES = RT * 3;
        const short8 bz = {0, 0, 0, 0, 0, 0, 0, 0};
        for (int tI = wave; tI < NTILES; tI += 4) {
            int tr = tI / 3, tc = tI - tr * 3;
            int gn = tc * 16 + mlane;
            bool okn = gn < 40;
            f32x4 acc = (f32x4){0.f, 0.f, 0.f, 0.f};
#pragma unroll
            for (int kk = 0; kk < 256; kk += 32) {
                short8 a = *(const short8*)&u_l[(tr * 16 + mlane) * UST + kk + koff];
                short8 b = okn ? *(const short8*)(xwp + (size_t)gn * 256 + kk + koff) : bz;
                acc = __builtin_amdgcn_mfma_f32_16x16x32_bf16(a, b, acc, 0, 0, 0);
            }
#pragma unroll
            for (int r = 0; r < 4; r++) {
                int s = tr * 16 + (lane >> 4) * 4 + r;
                if (okn && s < SLEN) qlds[s * 40 + gn] = acc[r];
            }
        }
    }

    f32x2 h2[8];
#pragma unroll
    for (int j = 0; j < 8; j++) h2[j] = (f32x2){0.f, 0.f};
    constexpr int NCH = (SLEN + 7) / 8;
    __syncthreads();

    float unxt[8], znxt[8];
    for (int c = 0; c < NCH; c++) {
        if (c + 1 < NCH) {
#pragma unroll
            for (int i = 0; i < 8; i++) {
                int st = (c + 1) * 8 + i; st = st < SLEN ? st : SLEN - 1;
                int s = rev ? (SLEN - 1 - st) : st;
                unxt[i] = __bfloat162float(u_l[s * UST + d]);
                znxt[i] = __bfloat162float(xz2[base + (size_t)s * 1024 + 256]);
            }
        }
#pragma unroll
        for (int i = 0; i < 8; i++) {
            int st = c * 8 + i;
            if (st < SLEN) {
                int s = rev ? (SLEN - 1 - st) : st;
                const float4* qv = (const float4*)&qlds[s * 40];
                float4 qa = qv[0], qb = qv[1];
                float uc_v = ucur[i];
                f32x2 acc2 = dw2[0] * (f32x2){qa.x, qa.y};
                acc2 += dw2[1] * (f32x2){qa.z, qa.w};
                acc2 += dw2[2] * (f32x2){qb.x, qb.y};
                acc2 += dw2[3] * (f32x2){qb.z, qb.w};
                float dtv = dbv + acc2.x + acc2.y;
                dtv = fmaxf(dtv, 0.f) + __logf(1.f + __expf(-fabsf(dtv)));
                float du = dtv * uc_v;
                float y;
                if (fast) {
                    float p1 = __expf(dtv * a0);
                    float p2 = p1 * p1;
                    f32x2 pp = (f32x2){p2, p2};
                    f32x2 e2[8];
                    e2[0] = (f32x2){p1, p2};
#pragma unroll
                    for (int j = 1; j < 8; j++) e2[j] = e2[j - 1] * pp;
                    f32x2 du2 = (f32x2){du, du};
                    f32x2 y2 = (f32x2){0.f, 0.f};
                    float4 B0 = qv[2], B1 = qv[3], B2 = qv[4], B3 = qv[5];
                    float4 C0 = qv[6], C1 = qv[7], C2 = qv[8], C3 = qv[9];
                    f32x2 bb[8] = {{B0.x, B0.y}, {B0.z, B0.w}, {B1.x, B1.y}, {B1.z, B1.w},
                                   {B2.x, B2.y}, {B2.z, B2.w}, {B3.x, B3.y}, {B3.z, B3.w}};
                    f32x2 cc[8] = {{C0.x, C0.y}, {C0.z, C0.w}, {C1.x, C1.y}, {C1.z, C1.w},
                                   {C2.x, C2.y}, {C2.z, C2.w}, {C3.x, C3.y}, {C3.z, C3.w}};
#pragma unroll
                    for (int j = 0; j < 8; j++) {
                        h2[j] = h2[j] * e2[j] + du2 * bb[j];
                        y2 += h2[j] * cc[j];
                    }
                    y = y2.x + y2.y;
                } else {
                    const float* q = &qlds[s * 40];
                    y = 0.f;
#pragma unroll
                    for (int j = 0; j < 16; j++) {
                        float e = __expf(dtv * (-__expf(al[j])));
                        float hh = h2[j >> 1][j & 1];
                        hh = hh * e + du * q[8 + j];
                        h2[j >> 1][j & 1] = hh;
                        y += hh * q[24 + j];
                    }
                }
                xz2[base + (size_t)s * 1024] =
                    __float2bfloat16((y + uc_v * Dv) * zcur[i]);
            }
        }
#pragma unroll
        for (int i = 0; i < 8; i++) { ucur[i] = unxt[i]; zcur[i] = znxt[i]; }
    }
}

// ============ token mix + LN (standalone, used for layer 0 only) ============
__global__ __launch_bounds__(256) void mix_ln_tok(const bf16* __restrict__ hb,
                                                 float* __restrict__ mixb, bf16* __restrict__ lnb_out,
                                                 const float* __restrict__ alpha,
                                                 const float* __restrict__ beta,
                                                 const float* __restrict__ lnw,
                                                 const float* __restrict__ lnb, int l) {
    int t = blockIdx.x * 4 + (threadIdx.x >> 6), d = threadIdx.x & 63;
    int cnt = l + 1;
    float aw[4], bw[4];
    float amax = -1e30f, bmax = -1e30f;
    for (int i = 0; i < cnt; i++) {
        aw[i] = alpha[l * 4 + i]; bw[i] = beta[l * 4 + i];
        amax = fmaxf(amax, aw[i]); bmax = fmaxf(bmax, bw[i]);
    }
    float as = 0.f, bs = 0.f;
    for (int i = 0; i < cnt; i++) {
        aw[i] = __expf(aw[i] - amax); as += aw[i];
        bw[i] = __expf(bw[i] - bmax); bs += bw[i];
    }
    float ai = 1.f / as, bi = 1.f / bs;
    float v0 = 0.f, v1 = 0.f;
    for (int i = 0; i < cnt; i++) {
        const bf16* yt = hb + (size_t)(i == 0 ? 0 : i) * HSZB + (size_t)t * 128 + 2 * d;
        const bf16* yc = hb + (size_t)(i == 0 ? 0 : 4 + i) * HSZB + (size_t)t * 128 + 2 * d;
        f32x2 vt = bfup2(yt), vc = bfup2(yc);
        float wa = aw[i] * ai, wb = bw[i] * bi;
        v0 += wa * vt.x + wb * vc.x;
        v1 += wa * vt.y + wb * vc.y;
    }
    *(f32x2*)&mixb[(size_t)t * 128 + 2 * d] = (f32x2){v0, v1};
    float s = v0 + v1, ss = v0 * v0 + v1 * v1;
#pragma unroll
    for (int o = 32; o >= 1; o >>= 1) { s += __shfl_xor(s, o); ss += __shfl_xor(ss, o); }
    float mean = s * (1.f / 128.f);
    float var  = ss * (1.f / 128.f) - mean * mean;
    float rstd = rsqrtf(var + 1e-5f);
    f32x2 w2 = *(const f32x2*)&lnw[2 * d];
    f32x2 b2 = *(const f32x2*)&lnb[2 * d];
    bfpack2((v0 - mean) * rstd * w2.x + b2.x,
            (v1 - mean) * rstd * w2.y + b2.y,
            lnb_out + (size_t)t * 128 + 2 * d);
}

// ============ LN over N=63, bf16 out ============
__global__ __launch_bounds__(256) void final_ln2(const float* __restrict__ in,
                                                 const float* __restrict__ w2,
                                                 const float* __restrict__ b2,
                                                 bf16* __restrict__ out) {
    int idx = blockIdx.x * 256 + threadIdx.x;
    if (idx >= BMq * Dq) return;
    int bm = idx >> 7, d = idx & 127;
    float s = 0.f, ss = 0.f;
    for (int n = 0; n < Nq; n++) {
        float v = in[((size_t)bm * Nq + n) * 128 + d];
        s += v; ss += v * v;
    }
    float mean = s * (1.f / (float)Nq);
    float var  = ss * (1.f / (float)Nq) - mean * mean;
    float rstd = rsqrtf(var + 1e-5f);
    for (int n = 0; n < Nq; n++) {
        float v = in[((size_t)bm * Nq + n) * 128 + d];
        out[((size_t)bm * Nq + n) * 128 + d] = __float2bfloat16((v - mean) * rstd * w2[n] + b2[n]);
    }
}

// ============ final: split-K reduce + bias + rescale + transpose ============
__global__ __launch_bounds__(256) void finalize_kernel(const float* __restrict__ part,
                                                       const float* __restrict__ bias,
                                                       const float* __restrict__ means,
                                                       const float* __restrict__ stds,
                                                       float* __restrict__ out) {
    int idx = blockIdx.x * 256 + threadIdx.x;
    if (idx >= Bq * PREDq * Mq) return;
    int b = idx / (PREDq * Mq);
    int r = idx - b * PREDq * Mq;
    int pr = r >> 5, m = r & 31;
    int bm = b * Mq + m;
    float s = bias[pr];
#pragma unroll
    for (int z = 0; z < 12; z++) s += part[(size_t)z * BMq * PREDq + (size_t)bm * PREDq + pr];
    out[idx] = s * stds[bm] + means[bm];
}

extern "C" void kernel_launch(void* const* d_in, const int* in_sizes, int n_in,
                              void* d_out, int out_size, void* d_ws, size_t ws_size,
                              hipStream_t stream) {
    if (ws_size < WS_FLOATS * sizeof(float)) return;

    const float* x          = (const float*)d_in[0];
    const float* patch_w    = (const float*)d_in[1];
    const float* patch_b    = (const float*)d_in[2];
    const float* pos_embed  = (const float*)d_in[3];
    const float* alpha      = (const float*)d_in[4];
    const float* beta       = (const float*)d_in[5];
    const float* theta      = (const float*)d_in[6];
    const float* gamma      = (const float*)d_in[7];
    const float* tok_norm_w = (const float*)d_in[8];
    const float* tok_norm_b = (const float*)d_in[9];
    const float* ch_norm_w  = (const float*)d_in[10];
    const float* ch_norm_b  = (const float*)d_in[11];
    const float* in_proj_w  = (const float*)d_in[12];
    const float* conv_w     = (const float*)d_in[13];
    const float* conv_b     = (const float*)d_in[14];
    const float* x_proj_w   = (const float*)d_in[15];
    const float* dt_proj_w  = (const float*)d_in[16];
    const float* dt_proj_b  = (const float*)d_in[17];
    const float* A_log      = (const float*)d_in[18];
    const float* D_ssm      = (const float*)d_in[19];
    const float* out_proj_w = (const float*)d_in[20];
    const float* n2d_w1     = (const float*)d_in[21];
    const float* n2d_b1     = (const float*)d_in[22];
    const float* n2d_w2     = (const float*)d_in[23];
    const float* n2d_b2     = (const float*)d_in[24];
    const float* head_w     = (const float*)d_in[25];
    const float* head_b     = (const float*)d_in[26];

    float* W   = (float*)d_ws;
    float* out = (float*)d_out;
    bf16* WB   = (bf16*)(W + OFF_WB);
    bf16* HB   = (bf16*)(W + OFF_HISTB);
    bf16* LNB  = (bf16*)(W + OFF_LNB);
    bf16* XZ2  = (bf16*)(W + OFF_XZ2);
    float* MIX = W + OFF_MIX;

    f2b_all<<<(WB_TOTAL + 255) / 256, 256, 0, stream>>>(
        in_proj_w, x_proj_w, out_proj_w, head_w, WB);

    stats_kernel<<<BMq, 256, 0, stream>>>(x, W + OFF_MEANS, W + OFF_STDS);
    patch_embed<<<TOKq, 128, 0, stream>>>(x, W + OFF_MEANS, W + OFF_STDS,
                                          patch_w, patch_b, pos_embed, HB);

    // layer-0 token mix (producer is patch_embed; later mixes are fused)
    mix_ln_tok<<<TOKq / 4, 256, 0, stream>>>(HB, MIX, LNB, alpha, beta,
                                             tok_norm_w, tok_norm_b, 0);

    for (int l = 0; l < NLq; l++) {
        size_t o0 = (size_t)(l * 3 + 0), o1 = (size_t)(l * 3 + 1), o2 = (size_t)(l * 3 + 2);

        // ================= token mamba =================
        gemm_in<<<dim3(4, 504), 256, 0, stream>>>(
            LNB, WB + WBE_IN + o0 * 65536, XZ2);
        scan_f<Nq, 64><<<BMq, 256, 0, stream>>>(
            XZ2, dt_proj_w + o0 * 2048, dt_proj_b + o0 * 256,
            A_log + o0 * 4096, D_ssm + o0 * 256,
            conv_w + o0 * 1024, conv_b + o0 * 256,
            WB + WBE_X + o0 * 10240, nullptr, BMq, 0);
        // out_proj tok + fused mix_ch(l) + LN
        gemm_mix<0, 0, 0><<<504, 256, 0, stream>>>(
            XZ2, WB + WBE_OUT + o0 * 32768, nullptr, MIX,
            HB, 1 + l, l, theta, gamma,
            ch_norm_w + l * Dq, ch_norm_b + l * Dq, MIX, LNB);

        // ================= channel mamba (fwd+bwd merged) =================
        gemm_in<<<dim3(8, 504), 256, 0, stream>>>(
            LNB, WB + WBE_IN + o1 * 65536, XZ2);
        scan_f<Mq, 32><<<2 * BNq, 256, 0, stream>>>(
            XZ2, dt_proj_w + o1 * 2048, dt_proj_b + o1 * 256,
            A_log + o1 * 4096, D_ssm + o1 * 256,
            conv_w + o1 * 1024, conv_b + o1 * 256,
            WB + WBE_X + o1 * 10240, WB + WBE_X + o2 * 10240, BNq, 1);
        // out_proj ch + fused mix_tok(l+1) (or Norm2D LN for last layer)
        if (l < NLq - 1) {
            gemm_mix<1, 1, 1><<<504, 256, 0, stream>>>(
                XZ2, WB + WBE_OUT + o1 * 32768, WB + WBE_OUT + o2 * 32768, MIX,
                HB, 5 + l, l, alpha, beta,
                tok_norm_w + (l + 1) * Dq, tok_norm_b + (l + 1) * Dq, MIX, LNB);
        } else {
            gemm_mix<1, 1, 2><<<504, 256, 0, stream>>>(
                XZ2, WB + WBE_OUT + o1 * 32768, WB + WBE_OUT + o2 * 32768, MIX,
                HB, 5 + l, l, nullptr, nullptr,
                n2d_w1, n2d_b1, MIX, nullptr);
        }
    }

    // ---- Norm2D pt2 + head ----
    final_ln2<<<(BMq * Dq + 255) / 256, 256, 0, stream>>>(MIX, n2d_w2, n2d_b2, LNB);
    gemm_k<0, 0, 64><<<dim3(2, 4, 12), 256, 0, stream>>>(
        LNB, Nq * Dq, WB + WBE_HEAD, nullptr, Nq * Dq, nullptr, 0,
        W + OFF_PART, nullptr, PREDq, BMq, PREDq, 672, 672,
        (size_t)BMq * PREDq, 0, 0, 0, nullptr, nullptr, 0, 0, 0, 0, nullptr);
    finalize_kernel<<<(Bq * PREDq * Mq + 255) / 256, 256, 0, stream>>>(
        W + OFF_PART, head_b, W + OFF_MEANS, W + OFF_STDS, out);
}